// Round 1
// baseline (1627.917 us; speedup 1.0000x reference)
//
#include <hip/hip_runtime.h>
#include <math.h>

// ---------------------------------------------------------------------------
// MandiFlowNet: GCNConv(128->64) -> ReLU -> GCNConv(64->64) -> ReLU ->
//               1-step LSTM (h0=c0=0) -> Linear(64->1)
// N=50000 nodes, E=800000 edges. All fp32 (threshold 1.4e-5 abs is ~2% rel).
// ---------------------------------------------------------------------------

__device__ __forceinline__ void atomAddF(float* p, float v) {
    // native global_atomic_add_f32, fire-and-forget, device scope
    __hip_atomic_fetch_add(p, v, __ATOMIC_RELAXED, __HIP_MEMORY_SCOPE_AGENT);
}

__device__ __forceinline__ float sigmoidf_(float x) {
    return 1.0f / (1.0f + expf(-x));
}

// deg[c] += ew[e]  (self-loop +1 folded into dis_k)
__global__ __launch_bounds__(256) void deg_accum_k(const int* __restrict__ col,
                                                   const float* __restrict__ ew,
                                                   float* __restrict__ deg, int E, int N) {
    int e = blockIdx.x * 256 + threadIdx.x;
    if (e < E) {
        int c = col[e];
        if ((unsigned)c < (unsigned)N) atomAddF(&deg[c], ew[e]);
    }
}

// dis[i] = rsqrt(deg[i] + 1)   (deg >= 1 always, so no zero guard needed)
__global__ __launch_bounds__(256) void dis_k(float* __restrict__ deg_dis, int N) {
    int i = blockIdx.x * 256 + threadIdx.x;
    if (i < N) deg_dis[i] = rsqrtf(deg_dis[i] + 1.0f);
}

// norm[e] = dis[row]*ew*dis[col]  (computed once, reused by both layers)
__global__ __launch_bounds__(256) void norm_k(const int* __restrict__ row,
                                              const int* __restrict__ col,
                                              const float* __restrict__ ew,
                                              const float* __restrict__ dis,
                                              float* __restrict__ norm, int E, int N) {
    int e = blockIdx.x * 256 + threadIdx.x;
    if (e < E) {
        int r = row[e], c = col[e];
        float dr = ((unsigned)r < (unsigned)N) ? dis[r] : 0.0f;
        float dc = ((unsigned)c < (unsigned)N) ? dis[c] : 0.0f;
        norm[e] = dr * ew[e] * dc;
    }
}

// C[M,64] = A[M,K] @ W[K,64], fp32, LDS-tiled. Block = 64 rows, 256 threads,
// each thread a 4x4 micro-tile. K staged in 64-wide slices (LDS budget).
template <int K>
__global__ __launch_bounds__(256) void gemm64_k(const float* __restrict__ A,
                                                const float* __restrict__ W,
                                                float* __restrict__ C, int M) {
    __shared__ float xs[64][68];    // +4 pad: 2-way max conflict, keeps 16B align
    __shared__ float ws[K][64];
    const int t  = threadIdx.x;
    const int n0 = blockIdx.x * 64;

    for (int base = t * 4; base < K * 64; base += 1024)
        *(float4*)((float*)ws + base) = *(const float4*)(W + base);

    const int cg = t & 15, ng = t >> 4;      // wave = 4 node-groups x 16 col-groups
    const int col = cg * 4, nb = ng * 4;
    float acc[4][4];
#pragma unroll
    for (int i = 0; i < 4; ++i)
#pragma unroll
        for (int j = 0; j < 4; ++j) acc[i][j] = 0.0f;

    for (int k0 = 0; k0 < K; k0 += 64) {
        __syncthreads();
        for (int base = t * 4; base < 64 * 64; base += 1024) {
            int r = base >> 6, k = base & 63;
            int node = n0 + r;
            float4 v = make_float4(0.f, 0.f, 0.f, 0.f);
            if (node < M) v = *(const float4*)(A + (size_t)node * K + k0 + k);
            *(float4*)&xs[r][k] = v;
        }
        __syncthreads();
#pragma unroll 4
        for (int kk = 0; kk < 64; kk += 4) {
            float4 a[4];
#pragma unroll
            for (int i = 0; i < 4; ++i) a[i] = *(float4*)&xs[nb + i][kk];
#pragma unroll
            for (int j = 0; j < 4; ++j) {
                float4 bv = *(float4*)&ws[k0 + kk + j][col];
                const float aj[4] = {a[0].x, a[1].x, a[2].x, a[3].x};
                float av[4];
                switch (j) {  // pick j-th lane of each a[i]
                    case 0: av[0]=a[0].x; av[1]=a[1].x; av[2]=a[2].x; av[3]=a[3].x; break;
                    case 1: av[0]=a[0].y; av[1]=a[1].y; av[2]=a[2].y; av[3]=a[3].y; break;
                    case 2: av[0]=a[0].z; av[1]=a[1].z; av[2]=a[2].z; av[3]=a[3].z; break;
                    default:av[0]=a[0].w; av[1]=a[1].w; av[2]=a[2].w; av[3]=a[3].w; break;
                }
                (void)aj;
#pragma unroll
                for (int i = 0; i < 4; ++i) {
                    acc[i][0] = fmaf(av[i], bv.x, acc[i][0]);
                    acc[i][1] = fmaf(av[i], bv.y, acc[i][1]);
                    acc[i][2] = fmaf(av[i], bv.z, acc[i][2]);
                    acc[i][3] = fmaf(av[i], bv.w, acc[i][3]);
                }
            }
        }
    }
#pragma unroll
    for (int i = 0; i < 4; ++i) {
        int node = n0 + nb + i;
        if (node < M)
            *(float4*)(C + (size_t)node * 64 + col) =
                make_float4(acc[i][0], acc[i][1], acc[i][2], acc[i][3]);
    }
}

// agg[col[e], :] += h[row[e], :] * norm[e]; 16 threads per edge, float4 each.
__global__ __launch_bounds__(256) void scatter_add_k(const float* __restrict__ h,
                                                     const int* __restrict__ row,
                                                     const int* __restrict__ col,
                                                     const float* __restrict__ norm,
                                                     float* __restrict__ agg,
                                                     int E, int N) {
    long long idx = (long long)blockIdx.x * 256 + threadIdx.x;
    long long e = idx >> 4;
    if (e >= E) return;
    int part = (int)(idx & 15);
    int r = row[e], c = col[e];
    if ((unsigned)r >= (unsigned)N || (unsigned)c >= (unsigned)N) return;
    float nv = norm[e];
    float4 v = *(const float4*)(h + (size_t)r * 64 + part * 4);
    float* dst = agg + (size_t)c * 64 + part * 4;
    atomAddF(dst + 0, v.x * nv);
    atomAddF(dst + 1, v.y * nv);
    atomAddF(dst + 2, v.z * nv);
    atomAddF(dst + 3, v.w * nv);
}

// in-place: agg = relu(agg + h*dis^2 + b)   (self-loop contribution h/deg)
__global__ __launch_bounds__(256) void epilogue_k(float* __restrict__ agg,
                                                  const float* __restrict__ h,
                                                  const float* __restrict__ dis,
                                                  const float* __restrict__ b, int N) {
    int idx = blockIdx.x * 256 + threadIdx.x;
    int node = idx >> 4;
    if (node >= N) return;
    int j = (idx & 15) * 4;
    float s = dis[node]; s = s * s;
    float4 a  = *(float4*)(agg + (size_t)node * 64 + j);
    float4 hv = *(const float4*)(h + (size_t)node * 64 + j);
    float4 bv = *(const float4*)(b + j);
    a.x = fmaxf(fmaf(hv.x, s, a.x) + bv.x, 0.0f);
    a.y = fmaxf(fmaf(hv.y, s, a.y) + bv.y, 0.0f);
    a.z = fmaxf(fmaf(hv.z, s, a.z) + bv.z, 0.0f);
    a.w = fmaxf(fmaf(hv.w, s, a.w) + bv.w, 0.0f);
    *(float4*)(agg + (size_t)node * 64 + j) = a;
}

// Fused 1-step LSTM (h0=c0=0 => W_hh term = 0, f-gate * c0 = 0 => skip f)
// + regression head. One wave per node; W_ih^T (i,g,o rows) staged in LDS.
__global__ __launch_bounds__(256) void lstm_head_k(const float* __restrict__ h,
                                                   const float* __restrict__ Wih,
                                                   const float* __restrict__ bih,
                                                   const float* __restrict__ bhh,
                                                   const float* __restrict__ Wreg,
                                                   const float* __restrict__ breg,
                                                   float* __restrict__ out, int N) {
    __shared__ float wi[64 * 64], wg[64 * 64], wo[64 * 64];
    __shared__ float bi[64], bg[64], bo[64], wr[64];
    __shared__ float hs[4][64];
    const int t = threadIdx.x;

    // Stage W_ih rows {i:0..63, g:128..191, o:192..255} transposed: w[k*64 + r]
    for (int base = t * 4; base < 4096; base += 1024) {
        int r = base >> 6, k = base & 63;
        float4 vi = *(const float4*)(Wih + (size_t)(0   + r) * 64 + k);
        float4 vg = *(const float4*)(Wih + (size_t)(128 + r) * 64 + k);
        float4 vo = *(const float4*)(Wih + (size_t)(192 + r) * 64 + k);
        wi[(k + 0) * 64 + r] = vi.x; wi[(k + 1) * 64 + r] = vi.y;
        wi[(k + 2) * 64 + r] = vi.z; wi[(k + 3) * 64 + r] = vi.w;
        wg[(k + 0) * 64 + r] = vg.x; wg[(k + 1) * 64 + r] = vg.y;
        wg[(k + 2) * 64 + r] = vg.z; wg[(k + 3) * 64 + r] = vg.w;
        wo[(k + 0) * 64 + r] = vo.x; wo[(k + 1) * 64 + r] = vo.y;
        wo[(k + 2) * 64 + r] = vo.z; wo[(k + 3) * 64 + r] = vo.w;
    }
    if (t < 64) {
        bi[t] = bih[t]       + bhh[t];
        bg[t] = bih[128 + t] + bhh[128 + t];
        bo[t] = bih[192 + t] + bhh[192 + t];
        wr[t] = Wreg[t];
    }
    const float br = breg[0];
    const int sub = t >> 6, lane = t & 63;

    for (int g0 = blockIdx.x * 4; g0 < N; g0 += gridDim.x * 4) {
        int node = g0 + sub;
        __syncthreads();   // also covers initial staging on first iteration
        hs[sub][lane] = (node < N) ? h[(size_t)node * 64 + lane] : 0.0f;
        __syncthreads();
        float ai = 0.f, ag = 0.f, ao = 0.f;
#pragma unroll 8
        for (int k = 0; k < 64; ++k) {
            float hv = hs[sub][k];  // wave-uniform broadcast
            ai = fmaf(hv, wi[k * 64 + lane], ai);
            ag = fmaf(hv, wg[k * 64 + lane], ag);
            ao = fmaf(hv, wo[k * 64 + lane], ao);
        }
        ai += bi[lane]; ag += bg[lane]; ao += bo[lane];
        float c  = sigmoidf_(ai) * tanhf(ag);
        float hn = sigmoidf_(ao) * tanhf(c);
        float v = hn * wr[lane];
#pragma unroll
        for (int off = 32; off > 0; off >>= 1) v += __shfl_down(v, off);
        if (lane == 0 && node < N) out[node] = v + br;
    }
}

extern "C" void kernel_launch(void* const* d_in, const int* in_sizes, int n_in,
                              void* d_out, int out_size, void* d_ws, size_t ws_size,
                              hipStream_t stream) {
    const float* x    = (const float*)d_in[0];
    const int*   ei   = (const int*)d_in[1];
    const float* ew   = (const float*)d_in[2];
    const float* W1   = (const float*)d_in[3];
    const float* b1   = (const float*)d_in[4];
    const float* W2   = (const float*)d_in[5];
    const float* b2   = (const float*)d_in[6];
    const float* Wih  = (const float*)d_in[7];
    // d_in[8] = W_hh: unused (h0 = 0)
    const float* bih  = (const float*)d_in[9];
    const float* bhh  = (const float*)d_in[10];
    const float* Wreg = (const float*)d_in[11];
    const float* breg = (const float*)d_in[12];
    float* out = (float*)d_out;

    const int N = out_size;            // O = 1
    const int E = in_sizes[1] / 2;
    const int* row = ei;
    const int* col = ei + E;

    float* ws = (float*)d_ws;
    size_t off = 0;
    float* dis  = ws + off; off += ((size_t)N + 63) & ~(size_t)63;
    float* nrm  = ws + off; off += ((size_t)E + 63) & ~(size_t)63;
    float* bufA = ws + off; off += (size_t)N * 64;
    float* bufB = ws + off; off += (size_t)N * 64;
    float* bufC = ws + off; off += (size_t)N * 64;

    const int eb = (E + 255) / 256;
    const int nb = (N + 255) / 256;
    const int sb = (int)(((long long)E * 16 + 255) / 256);
    const int pb = (N * 16 + 255) / 256;
    const int gb = (N + 63) / 64;

    // --- normalization precompute (shared by both layers) ---
    hipMemsetAsync(dis, 0, (size_t)N * sizeof(float), stream);
    deg_accum_k<<<eb, 256, 0, stream>>>(col, ew, dis, E, N);
    dis_k<<<nb, 256, 0, stream>>>(dis, N);
    norm_k<<<eb, 256, 0, stream>>>(row, col, ew, dis, nrm, E, N);

    // --- GCN layer 1 ---
    gemm64_k<128><<<gb, 256, 0, stream>>>(x, W1, bufA, N);
    hipMemsetAsync(bufB, 0, (size_t)N * 64 * sizeof(float), stream);
    scatter_add_k<<<sb, 256, 0, stream>>>(bufA, row, col, nrm, bufB, E, N);
    epilogue_k<<<pb, 256, 0, stream>>>(bufB, bufA, dis, b1, N);

    // --- GCN layer 2 ---
    gemm64_k<64><<<gb, 256, 0, stream>>>(bufB, W2, bufC, N);
    hipMemsetAsync(bufA, 0, (size_t)N * 64 * sizeof(float), stream);
    scatter_add_k<<<sb, 256, 0, stream>>>(bufC, row, col, nrm, bufA, E, N);
    epilogue_k<<<pb, 256, 0, stream>>>(bufA, bufC, dis, b2, N);

    // --- fused LSTM + regression head ---
    lstm_head_k<<<512, 256, 0, stream>>>(bufA, Wih, bih, bhh, Wreg, breg, out, N);
}

// Round 2
// 392.060 us; speedup vs baseline: 4.1522x; 4.1522x over previous
//
#include <hip/hip_runtime.h>
#include <math.h>

// ---------------------------------------------------------------------------
// MandiFlowNet: GCNConv(128->64) -> ReLU -> GCNConv(64->64) -> ReLU ->
//               1-step LSTM (h0=c0=0) -> Linear(64->1)
// N=50000 nodes, E=800000 edges. All fp32.
//
// R2: replaced atomic scatter (679us/layer, 819MB atomic write traffic) with
// CSR-by-destination build (counting sort) + per-node gather aggregation.
// Aggregation fuses self-loop + bias + ReLU (epilogue_k removed).
// ---------------------------------------------------------------------------

__device__ __forceinline__ float sigmoidf_(float x) {
    return 1.0f / (1.0f + expf(-x));
}

// histogram count + weighted degree, per destination node
__global__ __launch_bounds__(256) void deg_count_k(const int* __restrict__ col,
                                                   const float* __restrict__ ew,
                                                   float* __restrict__ deg,
                                                   int* __restrict__ cnt, int E, int N) {
    int e = blockIdx.x * 256 + threadIdx.x;
    if (e < E) {
        int c = col[e];
        if ((unsigned)c < (unsigned)N) {
            __hip_atomic_fetch_add(&deg[c], ew[e], __ATOMIC_RELAXED, __HIP_MEMORY_SCOPE_AGENT);
            __hip_atomic_fetch_add(&cnt[c], 1,     __ATOMIC_RELAXED, __HIP_MEMORY_SCOPE_AGENT);
        }
    }
}

// dis[i] = rsqrt(deg[i] + 1)   (+1 = self-loop weight)
__global__ __launch_bounds__(256) void dis_k(float* __restrict__ deg_dis, int N) {
    int i = blockIdx.x * 256 + threadIdx.x;
    if (i < N) deg_dis[i] = rsqrtf(deg_dis[i] + 1.0f);
}

// per-block sums of cnt -> bsum
__global__ __launch_bounds__(256) void scanA_k(const int* __restrict__ cnt,
                                               int* __restrict__ bsum, int N) {
    __shared__ int r[256];
    int t = threadIdx.x, i = blockIdx.x * 256 + t;
    r[t] = (i < N) ? cnt[i] : 0;
    __syncthreads();
#pragma unroll
    for (int off = 128; off > 0; off >>= 1) {
        if (t < off) r[t] += r[t + off];
        __syncthreads();
    }
    if (t == 0) bsum[blockIdx.x] = r[0];
}

// single-block exclusive scan of bsum[NB] (NB <= 256); writes rowptr[N] = E
__global__ __launch_bounds__(256) void scanB_k(int* __restrict__ bsum,
                                               int* __restrict__ rowptr, int NB, int N) {
    __shared__ int s[2][256];
    int t = threadIdx.x;
    int v = (t < NB) ? bsum[t] : 0;
    int pin = 0;
    s[0][t] = v;
    __syncthreads();
#pragma unroll
    for (int off = 1; off < 256; off <<= 1) {
        int x = s[pin][t];
        if (t >= off) x += s[pin][t - off];
        s[pin ^ 1][t] = x;
        pin ^= 1;
        __syncthreads();
    }
    int incl = s[pin][t];
    if (t < NB) bsum[t] = incl - v;     // exclusive block offset
    if (t == 255) rowptr[N] = incl;     // total = E
}

// in-block exclusive scan of cnt + block offset -> rowptr, cursor
__global__ __launch_bounds__(256) void scanC_k(const int* __restrict__ cnt,
                                               const int* __restrict__ bsum,
                                               int* __restrict__ rowptr,
                                               int* __restrict__ cursor, int N) {
    __shared__ int s[2][256];
    int t = threadIdx.x, i = blockIdx.x * 256 + t;
    int v = (i < N) ? cnt[i] : 0;
    int pin = 0;
    s[0][t] = v;
    __syncthreads();
#pragma unroll
    for (int off = 1; off < 256; off <<= 1) {
        int x = s[pin][t];
        if (t >= off) x += s[pin][t - off];
        s[pin ^ 1][t] = x;
        pin ^= 1;
        __syncthreads();
    }
    int excl = s[pin][t] - v + bsum[blockIdx.x];
    if (i < N) { rowptr[i] = excl; cursor[i] = excl; }
}

// fill CSR: srcs/vals in destination-sorted order; norm computed on the fly
__global__ __launch_bounds__(256) void fill_k(const int* __restrict__ row,
                                              const int* __restrict__ col,
                                              const float* __restrict__ ew,
                                              const float* __restrict__ dis,
                                              int* __restrict__ cursor,
                                              int* __restrict__ srcs,
                                              float* __restrict__ vals, int E, int N) {
    int e = blockIdx.x * 256 + threadIdx.x;
    if (e >= E) return;
    int r = row[e], c = col[e];
    if ((unsigned)r >= (unsigned)N || (unsigned)c >= (unsigned)N) return;
    float nv = dis[r] * ew[e] * dis[c];
    int pos = __hip_atomic_fetch_add(&cursor[c], 1, __ATOMIC_RELAXED, __HIP_MEMORY_SCOPE_AGENT);
    srcs[pos] = r;
    vals[pos] = nv;
}

// out[c,:] = relu( sum_e h[src_e,:]*val_e + h[c,:]*dis[c]^2 + b )
// one wave per node, lane = feature; edge (src,val) loaded lane-parallel,
// broadcast via shfl; gathers 4-deep for memory-level parallelism.
__global__ __launch_bounds__(256) void aggregate_k(const float* __restrict__ h,
                                                   const int* __restrict__ rowptr,
                                                   const int* __restrict__ srcs,
                                                   const float* __restrict__ vals,
                                                   const float* __restrict__ dis,
                                                   const float* __restrict__ b,
                                                   float* __restrict__ out, int N) {
    const int t = threadIdx.x;
    const int lane = t & 63;
    const int node = blockIdx.x * 4 + (t >> 6);
    if (node >= N) return;

    const int beg = rowptr[node], end = rowptr[node + 1];
    float acc = 0.0f;
    for (int base = beg; base < end; base += 64) {
        int n = min(64, end - base);
        int src = 0; float val = 0.0f;
        if (lane < n) { src = srcs[base + lane]; val = vals[base + lane]; }
        int j = 0;
        for (; j + 4 <= n; j += 4) {
            int   s0 = __shfl(src, j),     s1 = __shfl(src, j + 1);
            int   s2 = __shfl(src, j + 2), s3 = __shfl(src, j + 3);
            float v0 = __shfl(val, j),     v1 = __shfl(val, j + 1);
            float v2 = __shfl(val, j + 2), v3 = __shfl(val, j + 3);
            float h0 = h[(size_t)s0 * 64 + lane];
            float h1 = h[(size_t)s1 * 64 + lane];
            float h2 = h[(size_t)s2 * 64 + lane];
            float h3 = h[(size_t)s3 * 64 + lane];
            acc = fmaf(h0, v0, acc);
            acc = fmaf(h1, v1, acc);
            acc = fmaf(h2, v2, acc);
            acc = fmaf(h3, v3, acc);
        }
        for (; j < n; ++j) {
            int s0 = __shfl(src, j);
            float v0 = __shfl(val, j);
            acc = fmaf(h[(size_t)s0 * 64 + lane], v0, acc);
        }
    }
    float d = dis[node];
    acc = fmaf(h[(size_t)node * 64 + lane], d * d, acc) + b[lane];
    out[(size_t)node * 64 + lane] = fmaxf(acc, 0.0f);
}

// C[M,64] = A[M,K] @ W[K,64], fp32, LDS-tiled. Block = 64 rows, 256 threads,
// each thread a 4x4 micro-tile.
template <int K>
__global__ __launch_bounds__(256) void gemm64_k(const float* __restrict__ A,
                                                const float* __restrict__ W,
                                                float* __restrict__ C, int M) {
    __shared__ float xs[64][68];
    __shared__ float ws[K][64];
    const int t  = threadIdx.x;
    const int n0 = blockIdx.x * 64;

    for (int base = t * 4; base < K * 64; base += 1024)
        *(float4*)((float*)ws + base) = *(const float4*)(W + base);

    const int cg = t & 15, ng = t >> 4;
    const int col = cg * 4, nb = ng * 4;
    float acc[4][4];
#pragma unroll
    for (int i = 0; i < 4; ++i)
#pragma unroll
        for (int j = 0; j < 4; ++j) acc[i][j] = 0.0f;

    for (int k0 = 0; k0 < K; k0 += 64) {
        __syncthreads();
        for (int base = t * 4; base < 64 * 64; base += 1024) {
            int r = base >> 6, k = base & 63;
            int node = n0 + r;
            float4 v = make_float4(0.f, 0.f, 0.f, 0.f);
            if (node < M) v = *(const float4*)(A + (size_t)node * K + k0 + k);
            *(float4*)&xs[r][k] = v;
        }
        __syncthreads();
#pragma unroll 4
        for (int kk = 0; kk < 64; kk += 4) {
            float4 a[4];
#pragma unroll
            for (int i = 0; i < 4; ++i) a[i] = *(float4*)&xs[nb + i][kk];
#pragma unroll
            for (int j = 0; j < 4; ++j) {
                float4 bv = *(float4*)&ws[k0 + kk + j][col];
                float av[4];
                switch (j) {
                    case 0: av[0]=a[0].x; av[1]=a[1].x; av[2]=a[2].x; av[3]=a[3].x; break;
                    case 1: av[0]=a[0].y; av[1]=a[1].y; av[2]=a[2].y; av[3]=a[3].y; break;
                    case 2: av[0]=a[0].z; av[1]=a[1].z; av[2]=a[2].z; av[3]=a[3].z; break;
                    default:av[0]=a[0].w; av[1]=a[1].w; av[2]=a[2].w; av[3]=a[3].w; break;
                }
#pragma unroll
                for (int i = 0; i < 4; ++i) {
                    acc[i][0] = fmaf(av[i], bv.x, acc[i][0]);
                    acc[i][1] = fmaf(av[i], bv.y, acc[i][1]);
                    acc[i][2] = fmaf(av[i], bv.z, acc[i][2]);
                    acc[i][3] = fmaf(av[i], bv.w, acc[i][3]);
                }
            }
        }
    }
#pragma unroll
    for (int i = 0; i < 4; ++i) {
        int node = n0 + nb + i;
        if (node < M)
            *(float4*)(C + (size_t)node * 64 + col) =
                make_float4(acc[i][0], acc[i][1], acc[i][2], acc[i][3]);
    }
}

// Fused 1-step LSTM (h0=c0=0 => skip W_hh and f-gate) + regression head.
__global__ __launch_bounds__(256) void lstm_head_k(const float* __restrict__ h,
                                                   const float* __restrict__ Wih,
                                                   const float* __restrict__ bih,
                                                   const float* __restrict__ bhh,
                                                   const float* __restrict__ Wreg,
                                                   const float* __restrict__ breg,
                                                   float* __restrict__ out, int N) {
    __shared__ float wi[64 * 64], wg[64 * 64], wo[64 * 64];
    __shared__ float bi[64], bg[64], bo[64], wr[64];
    __shared__ float hs[4][64];
    const int t = threadIdx.x;

    for (int base = t * 4; base < 4096; base += 1024) {
        int r = base >> 6, k = base & 63;
        float4 vi = *(const float4*)(Wih + (size_t)(0   + r) * 64 + k);
        float4 vg = *(const float4*)(Wih + (size_t)(128 + r) * 64 + k);
        float4 vo = *(const float4*)(Wih + (size_t)(192 + r) * 64 + k);
        wi[(k + 0) * 64 + r] = vi.x; wi[(k + 1) * 64 + r] = vi.y;
        wi[(k + 2) * 64 + r] = vi.z; wi[(k + 3) * 64 + r] = vi.w;
        wg[(k + 0) * 64 + r] = vg.x; wg[(k + 1) * 64 + r] = vg.y;
        wg[(k + 2) * 64 + r] = vg.z; wg[(k + 3) * 64 + r] = vg.w;
        wo[(k + 0) * 64 + r] = vo.x; wo[(k + 1) * 64 + r] = vo.y;
        wo[(k + 2) * 64 + r] = vo.z; wo[(k + 3) * 64 + r] = vo.w;
    }
    if (t < 64) {
        bi[t] = bih[t]       + bhh[t];
        bg[t] = bih[128 + t] + bhh[128 + t];
        bo[t] = bih[192 + t] + bhh[192 + t];
        wr[t] = Wreg[t];
    }
    const float br = breg[0];
    const int sub = t >> 6, lane = t & 63;

    for (int g0 = blockIdx.x * 4; g0 < N; g0 += gridDim.x * 4) {
        int node = g0 + sub;
        __syncthreads();
        hs[sub][lane] = (node < N) ? h[(size_t)node * 64 + lane] : 0.0f;
        __syncthreads();
        float ai = 0.f, ag = 0.f, ao = 0.f;
#pragma unroll 8
        for (int k = 0; k < 64; ++k) {
            float hv = hs[sub][k];
            ai = fmaf(hv, wi[k * 64 + lane], ai);
            ag = fmaf(hv, wg[k * 64 + lane], ag);
            ao = fmaf(hv, wo[k * 64 + lane], ao);
        }
        ai += bi[lane]; ag += bg[lane]; ao += bo[lane];
        float c  = sigmoidf_(ai) * tanhf(ag);
        float hn = sigmoidf_(ao) * tanhf(c);
        float v = hn * wr[lane];
#pragma unroll
        for (int off = 32; off > 0; off >>= 1) v += __shfl_down(v, off);
        if (lane == 0 && node < N) out[node] = v + br;
    }
}

extern "C" void kernel_launch(void* const* d_in, const int* in_sizes, int n_in,
                              void* d_out, int out_size, void* d_ws, size_t ws_size,
                              hipStream_t stream) {
    const float* x    = (const float*)d_in[0];
    const int*   ei   = (const int*)d_in[1];
    const float* ew   = (const float*)d_in[2];
    const float* W1   = (const float*)d_in[3];
    const float* b1   = (const float*)d_in[4];
    const float* W2   = (const float*)d_in[5];
    const float* b2   = (const float*)d_in[6];
    const float* Wih  = (const float*)d_in[7];
    // d_in[8] = W_hh: unused (h0 = 0)
    const float* bih  = (const float*)d_in[9];
    const float* bhh  = (const float*)d_in[10];
    const float* Wreg = (const float*)d_in[11];
    const float* breg = (const float*)d_in[12];
    float* out = (float*)d_out;

    const int N = out_size;            // O = 1
    const int E = in_sizes[1] / 2;
    const int* row = ei;
    const int* col = ei + E;

    const int NB = (N + 255) / 256;    // 196 blocks over nodes
    const int Np = (N + 63) & ~63;
    const int Ep = (E + 63) & ~63;

    char* wsb = (char*)d_ws;
    size_t off = 0;
    float* dis    = (float*)(wsb + off); off += (size_t)Np * 4;
    int*   cnt    = (int*)  (wsb + off); off += (size_t)Np * 4;
    int*   rowptr = (int*)  (wsb + off); off += ((size_t)Np + 64) * 4;
    int*   cursor = (int*)  (wsb + off); off += (size_t)Np * 4;
    int*   bsum   = (int*)  (wsb + off); off += 256 * 4;
    int*   srcs   = (int*)  (wsb + off); off += (size_t)Ep * 4;
    float* vals   = (float*)(wsb + off); off += (size_t)Ep * 4;
    float* bufA   = (float*)(wsb + off); off += (size_t)N * 64 * 4;
    float* bufB   = (float*)(wsb + off); off += (size_t)N * 64 * 4;
    float* bufC   = (float*)(wsb + off); off += (size_t)N * 64 * 4;

    const int eb = (E + 255) / 256;
    const int gb = (N + 63) / 64;
    const int ab = (N + 3) / 4;

    // --- CSR-by-destination build + normalization (shared by both layers) ---
    hipMemsetAsync(dis, 0, (size_t)Np * sizeof(float), stream);
    hipMemsetAsync(cnt, 0, (size_t)Np * sizeof(int), stream);
    deg_count_k<<<eb, 256, 0, stream>>>(col, ew, dis, cnt, E, N);
    dis_k<<<NB, 256, 0, stream>>>(dis, N);
    scanA_k<<<NB, 256, 0, stream>>>(cnt, bsum, N);
    scanB_k<<<1, 256, 0, stream>>>(bsum, rowptr, NB, N);
    scanC_k<<<NB, 256, 0, stream>>>(cnt, bsum, rowptr, cursor, N);
    fill_k<<<eb, 256, 0, stream>>>(row, col, ew, dis, cursor, srcs, vals, E, N);

    // --- GCN layer 1 ---
    gemm64_k<128><<<gb, 256, 0, stream>>>(x, W1, bufA, N);
    aggregate_k<<<ab, 256, 0, stream>>>(bufA, rowptr, srcs, vals, dis, b1, bufB, N);

    // --- GCN layer 2 ---
    gemm64_k<64><<<gb, 256, 0, stream>>>(bufB, W2, bufC, N);
    aggregate_k<<<ab, 256, 0, stream>>>(bufC, rowptr, srcs, vals, dis, b2, bufA, N);

    // --- fused LSTM + regression head ---
    lstm_head_k<<<512, 256, 0, stream>>>(bufA, Wih, bih, bhh, Wreg, breg, out, N);
}

// Round 3
// 350.576 us; speedup vs baseline: 4.6436x; 1.1183x over previous
//
#include <hip/hip_runtime.h>
#include <math.h>

// ---------------------------------------------------------------------------
// MandiFlowNet: GCNConv(128->64) -> ReLU -> GCNConv(64->64) -> ReLU ->
//               1-step LSTM (h0=c0=0) -> Linear(64->1)
// N=50000 nodes, E=800000 edges. All fp32.
//
// R2: CSR-by-destination build + gather aggregation (replaced 679us atomic
//     scatter).
// R3: lstm_head_k rewritten as register-blocked GEMM tile: 4x4 micro-tile
//     per gate per thread, hsT stored transposed so node-activations read as
//     one ds_read_b128. Was 1:1 LDS:FMA inst ratio + 2.9M bank conflicts
//     (76.8us); now 1:12 and conflict-free (predicted ~12us).
// ---------------------------------------------------------------------------

__device__ __forceinline__ float sigmoidf_(float x) {
    return 1.0f / (1.0f + expf(-x));
}

// histogram count + weighted degree, per destination node
__global__ __launch_bounds__(256) void deg_count_k(const int* __restrict__ col,
                                                   const float* __restrict__ ew,
                                                   float* __restrict__ deg,
                                                   int* __restrict__ cnt, int E, int N) {
    int e = blockIdx.x * 256 + threadIdx.x;
    if (e < E) {
        int c = col[e];
        if ((unsigned)c < (unsigned)N) {
            __hip_atomic_fetch_add(&deg[c], ew[e], __ATOMIC_RELAXED, __HIP_MEMORY_SCOPE_AGENT);
            __hip_atomic_fetch_add(&cnt[c], 1,     __ATOMIC_RELAXED, __HIP_MEMORY_SCOPE_AGENT);
        }
    }
}

// dis[i] = rsqrt(deg[i] + 1)   (+1 = self-loop weight)
__global__ __launch_bounds__(256) void dis_k(float* __restrict__ deg_dis, int N) {
    int i = blockIdx.x * 256 + threadIdx.x;
    if (i < N) deg_dis[i] = rsqrtf(deg_dis[i] + 1.0f);
}

// per-block sums of cnt -> bsum
__global__ __launch_bounds__(256) void scanA_k(const int* __restrict__ cnt,
                                               int* __restrict__ bsum, int N) {
    __shared__ int r[256];
    int t = threadIdx.x, i = blockIdx.x * 256 + t;
    r[t] = (i < N) ? cnt[i] : 0;
    __syncthreads();
#pragma unroll
    for (int off = 128; off > 0; off >>= 1) {
        if (t < off) r[t] += r[t + off];
        __syncthreads();
    }
    if (t == 0) bsum[blockIdx.x] = r[0];
}

// single-block exclusive scan of bsum[NB] (NB <= 256); writes rowptr[N] = E
__global__ __launch_bounds__(256) void scanB_k(int* __restrict__ bsum,
                                               int* __restrict__ rowptr, int NB, int N) {
    __shared__ int s[2][256];
    int t = threadIdx.x;
    int v = (t < NB) ? bsum[t] : 0;
    int pin = 0;
    s[0][t] = v;
    __syncthreads();
#pragma unroll
    for (int off = 1; off < 256; off <<= 1) {
        int x = s[pin][t];
        if (t >= off) x += s[pin][t - off];
        s[pin ^ 1][t] = x;
        pin ^= 1;
        __syncthreads();
    }
    int incl = s[pin][t];
    if (t < NB) bsum[t] = incl - v;     // exclusive block offset
    if (t == 255) rowptr[N] = incl;     // total = E
}

// in-block exclusive scan of cnt + block offset -> rowptr, cursor
__global__ __launch_bounds__(256) void scanC_k(const int* __restrict__ cnt,
                                               const int* __restrict__ bsum,
                                               int* __restrict__ rowptr,
                                               int* __restrict__ cursor, int N) {
    __shared__ int s[2][256];
    int t = threadIdx.x, i = blockIdx.x * 256 + t;
    int v = (i < N) ? cnt[i] : 0;
    int pin = 0;
    s[0][t] = v;
    __syncthreads();
#pragma unroll
    for (int off = 1; off < 256; off <<= 1) {
        int x = s[pin][t];
        if (t >= off) x += s[pin][t - off];
        s[pin ^ 1][t] = x;
        pin ^= 1;
        __syncthreads();
    }
    int excl = s[pin][t] - v + bsum[blockIdx.x];
    if (i < N) { rowptr[i] = excl; cursor[i] = excl; }
}

// fill CSR: srcs/vals in destination-sorted order; norm computed on the fly
__global__ __launch_bounds__(256) void fill_k(const int* __restrict__ row,
                                              const int* __restrict__ col,
                                              const float* __restrict__ ew,
                                              const float* __restrict__ dis,
                                              int* __restrict__ cursor,
                                              int* __restrict__ srcs,
                                              float* __restrict__ vals, int E, int N) {
    int e = blockIdx.x * 256 + threadIdx.x;
    if (e >= E) return;
    int r = row[e], c = col[e];
    if ((unsigned)r >= (unsigned)N || (unsigned)c >= (unsigned)N) return;
    float nv = dis[r] * ew[e] * dis[c];
    int pos = __hip_atomic_fetch_add(&cursor[c], 1, __ATOMIC_RELAXED, __HIP_MEMORY_SCOPE_AGENT);
    srcs[pos] = r;
    vals[pos] = nv;
}

// out[c,:] = relu( sum_e h[src_e,:]*val_e + h[c,:]*dis[c]^2 + b )
// one wave per node, lane = feature; edge (src,val) loaded lane-parallel,
// broadcast via shfl; gathers 4-deep for memory-level parallelism.
__global__ __launch_bounds__(256) void aggregate_k(const float* __restrict__ h,
                                                   const int* __restrict__ rowptr,
                                                   const int* __restrict__ srcs,
                                                   const float* __restrict__ vals,
                                                   const float* __restrict__ dis,
                                                   const float* __restrict__ b,
                                                   float* __restrict__ out, int N) {
    const int t = threadIdx.x;
    const int lane = t & 63;
    const int node = blockIdx.x * 4 + (t >> 6);
    if (node >= N) return;

    const int beg = rowptr[node], end = rowptr[node + 1];
    float acc = 0.0f;
    for (int base = beg; base < end; base += 64) {
        int n = min(64, end - base);
        int src = 0; float val = 0.0f;
        if (lane < n) { src = srcs[base + lane]; val = vals[base + lane]; }
        int j = 0;
        for (; j + 4 <= n; j += 4) {
            int   s0 = __shfl(src, j),     s1 = __shfl(src, j + 1);
            int   s2 = __shfl(src, j + 2), s3 = __shfl(src, j + 3);
            float v0 = __shfl(val, j),     v1 = __shfl(val, j + 1);
            float v2 = __shfl(val, j + 2), v3 = __shfl(val, j + 3);
            float h0 = h[(size_t)s0 * 64 + lane];
            float h1 = h[(size_t)s1 * 64 + lane];
            float h2 = h[(size_t)s2 * 64 + lane];
            float h3 = h[(size_t)s3 * 64 + lane];
            acc = fmaf(h0, v0, acc);
            acc = fmaf(h1, v1, acc);
            acc = fmaf(h2, v2, acc);
            acc = fmaf(h3, v3, acc);
        }
        for (; j < n; ++j) {
            int s0 = __shfl(src, j);
            float v0 = __shfl(val, j);
            acc = fmaf(h[(size_t)s0 * 64 + lane], v0, acc);
        }
    }
    float d = dis[node];
    acc = fmaf(h[(size_t)node * 64 + lane], d * d, acc) + b[lane];
    out[(size_t)node * 64 + lane] = fmaxf(acc, 0.0f);
}

// C[M,64] = A[M,K] @ W[K,64], fp32, LDS-tiled. Block = 64 rows, 256 threads,
// each thread a 4x4 micro-tile.
template <int K>
__global__ __launch_bounds__(256) void gemm64_k(const float* __restrict__ A,
                                                const float* __restrict__ W,
                                                float* __restrict__ C, int M) {
    __shared__ float xs[64][68];
    __shared__ float ws[K][64];
    const int t  = threadIdx.x;
    const int n0 = blockIdx.x * 64;

    for (int base = t * 4; base < K * 64; base += 1024)
        *(float4*)((float*)ws + base) = *(const float4*)(W + base);

    const int cg = t & 15, ng = t >> 4;
    const int col = cg * 4, nb = ng * 4;
    float acc[4][4];
#pragma unroll
    for (int i = 0; i < 4; ++i)
#pragma unroll
        for (int j = 0; j < 4; ++j) acc[i][j] = 0.0f;

    for (int k0 = 0; k0 < K; k0 += 64) {
        __syncthreads();
        for (int base = t * 4; base < 64 * 64; base += 1024) {
            int r = base >> 6, k = base & 63;
            int node = n0 + r;
            float4 v = make_float4(0.f, 0.f, 0.f, 0.f);
            if (node < M) v = *(const float4*)(A + (size_t)node * K + k0 + k);
            *(float4*)&xs[r][k] = v;
        }
        __syncthreads();
#pragma unroll 4
        for (int kk = 0; kk < 64; kk += 4) {
            float4 a[4];
#pragma unroll
            for (int i = 0; i < 4; ++i) a[i] = *(float4*)&xs[nb + i][kk];
#pragma unroll
            for (int j = 0; j < 4; ++j) {
                float4 bv = *(float4*)&ws[k0 + kk + j][col];
                float av[4];
                switch (j) {
                    case 0: av[0]=a[0].x; av[1]=a[1].x; av[2]=a[2].x; av[3]=a[3].x; break;
                    case 1: av[0]=a[0].y; av[1]=a[1].y; av[2]=a[2].y; av[3]=a[3].y; break;
                    case 2: av[0]=a[0].z; av[1]=a[1].z; av[2]=a[2].z; av[3]=a[3].z; break;
                    default:av[0]=a[0].w; av[1]=a[1].w; av[2]=a[2].w; av[3]=a[3].w; break;
                }
#pragma unroll
                for (int i = 0; i < 4; ++i) {
                    acc[i][0] = fmaf(av[i], bv.x, acc[i][0]);
                    acc[i][1] = fmaf(av[i], bv.y, acc[i][1]);
                    acc[i][2] = fmaf(av[i], bv.z, acc[i][2]);
                    acc[i][3] = fmaf(av[i], bv.w, acc[i][3]);
                }
            }
        }
    }
#pragma unroll
    for (int i = 0; i < 4; ++i) {
        int node = n0 + nb + i;
        if (node < M)
            *(float4*)(C + (size_t)node * 64 + col) =
                make_float4(acc[i][0], acc[i][1], acc[i][2], acc[i][3]);
    }
}

// Fused 1-step LSTM (h0=c0=0 => skip W_hh and f-gate) + regression head.
// Register-blocked GEMM tile: 64 nodes/block, thread = 4 nodes x 4 cols x
// {i,g,o}. hsT[k][node] transposed so 4 node-activations = one float4 read.
// LDS = 48KB (W^T, stride 192, conflict-free) + 16KB (hsT) = 64KB exactly.
__global__ __launch_bounds__(256) void lstm_head_k(const float* __restrict__ h,
                                                   const float* __restrict__ Wih,
                                                   const float* __restrict__ bih,
                                                   const float* __restrict__ bhh,
                                                   const float* __restrict__ Wreg,
                                                   const float* __restrict__ breg,
                                                   float* __restrict__ out, int N) {
    __shared__ float wt[64 * 192];   // wt[k*192 + gateOff + j] = Wih[gBase+j][k]
    __shared__ float hsT[64 * 64];   // hsT[k*64 + r] = h[n0+r][k]
    const int t = threadIdx.x;
    const int n0 = blockIdx.x * 64;

    // --- stage W^T: lanes write consecutive j => conflict-free ---
    {
        const int j = t & 63, kq = (t >> 6) * 4;   // kq in {0,4,8,12}
#pragma unroll
        for (int gid = 0; gid < 3; ++gid) {
            const int gBase = (gid == 0) ? 0 : (gid == 1 ? 128 : 192);  // i,g,o
            const int gOff = gid * 64;
#pragma unroll
            for (int it = 0; it < 4; ++it) {
                int k0 = it * 16 + kq;
                float4 w = *(const float4*)(Wih + (size_t)(gBase + j) * 64 + k0);
                wt[(k0 + 0) * 192 + gOff + j] = w.x;
                wt[(k0 + 1) * 192 + gOff + j] = w.y;
                wt[(k0 + 2) * 192 + gOff + j] = w.z;
                wt[(k0 + 3) * 192 + gOff + j] = w.w;
            }
        }
    }
    // --- stage h tile transposed ---
    {
        const int r = t & 63, kq = (t >> 6) * 4;
        const int node = n0 + r;
#pragma unroll
        for (int it = 0; it < 4; ++it) {
            int k0 = it * 16 + kq;
            float4 v = make_float4(0.f, 0.f, 0.f, 0.f);
            if (node < N) v = *(const float4*)(h + (size_t)node * 64 + k0);
            hsT[(k0 + 0) * 64 + r] = v.x;
            hsT[(k0 + 1) * 64 + r] = v.y;
            hsT[(k0 + 2) * 64 + r] = v.z;
            hsT[(k0 + 3) * 64 + r] = v.w;
        }
    }

    // --- per-thread biases & head weights in registers ---
    const int cg = t & 15, ng = t >> 4;
    const int col = cg * 4, nb = ng * 4;
    float4 bi4 = *(const float4*)(bih + col);
    float4 bg4 = *(const float4*)(bih + 128 + col);
    float4 bo4 = *(const float4*)(bih + 192 + col);
    {
        float4 h0 = *(const float4*)(bhh + col);
        float4 h1 = *(const float4*)(bhh + 128 + col);
        float4 h2 = *(const float4*)(bhh + 192 + col);
        bi4.x += h0.x; bi4.y += h0.y; bi4.z += h0.z; bi4.w += h0.w;
        bg4.x += h1.x; bg4.y += h1.y; bg4.z += h1.z; bg4.w += h1.w;
        bo4.x += h2.x; bo4.y += h2.y; bo4.z += h2.z; bo4.w += h2.w;
    }
    float4 wr4 = *(const float4*)(Wreg + col);
    const float br = breg[0];

    __syncthreads();

    float ai[4][4], ag[4][4], ao[4][4];
#pragma unroll
    for (int i = 0; i < 4; ++i)
#pragma unroll
        for (int j = 0; j < 4; ++j) { ai[i][j] = 0.f; ag[i][j] = 0.f; ao[i][j] = 0.f; }

#pragma unroll 4
    for (int k = 0; k < 64; ++k) {
        float4 a  = *(float4*)&hsT[k * 64 + nb];         // 4 nodes @ feature k
        float4 wi = *(float4*)&wt[k * 192 + col];        // i-gate cols
        float4 wg = *(float4*)&wt[k * 192 + 64 + col];   // g-gate cols
        float4 wo = *(float4*)&wt[k * 192 + 128 + col];  // o-gate cols
        const float av[4] = {a.x, a.y, a.z, a.w};
#pragma unroll
        for (int i = 0; i < 4; ++i) {
            ai[i][0] = fmaf(av[i], wi.x, ai[i][0]);
            ai[i][1] = fmaf(av[i], wi.y, ai[i][1]);
            ai[i][2] = fmaf(av[i], wi.z, ai[i][2]);
            ai[i][3] = fmaf(av[i], wi.w, ai[i][3]);
            ag[i][0] = fmaf(av[i], wg.x, ag[i][0]);
            ag[i][1] = fmaf(av[i], wg.y, ag[i][1]);
            ag[i][2] = fmaf(av[i], wg.z, ag[i][2]);
            ag[i][3] = fmaf(av[i], wg.w, ag[i][3]);
            ao[i][0] = fmaf(av[i], wo.x, ao[i][0]);
            ao[i][1] = fmaf(av[i], wo.y, ao[i][1]);
            ao[i][2] = fmaf(av[i], wo.z, ao[i][2]);
            ao[i][3] = fmaf(av[i], wo.w, ao[i][3]);
        }
    }

    // --- epilogue: nonlinearities + head dot-product ---
    const float bia[4] = {bi4.x, bi4.y, bi4.z, bi4.w};
    const float bga[4] = {bg4.x, bg4.y, bg4.z, bg4.w};
    const float boa[4] = {bo4.x, bo4.y, bo4.z, bo4.w};
    const float wra[4] = {wr4.x, wr4.y, wr4.z, wr4.w};
    float res[4];
#pragma unroll
    for (int i = 0; i < 4; ++i) {
        float s = 0.f;
#pragma unroll
        for (int j = 0; j < 4; ++j) {
            float gi = ai[i][j] + bia[j];
            float gg = ag[i][j] + bga[j];
            float go = ao[i][j] + boa[j];
            float cc = sigmoidf_(gi) * tanhf(gg);
            float hn = sigmoidf_(go) * tanhf(cc);
            s = fmaf(hn, wra[j], s);
        }
        res[i] = s;
    }
    // reduce across the 16 col-groups (contiguous lanes within the wave)
#pragma unroll
    for (int off = 8; off > 0; off >>= 1) {
#pragma unroll
        for (int i = 0; i < 4; ++i) res[i] += __shfl_down(res[i], off);
    }
    if (cg == 0) {
#pragma unroll
        for (int i = 0; i < 4; ++i) {
            int node = n0 + nb + i;
            if (node < N) out[node] = res[i] + br;
        }
    }
}

extern "C" void kernel_launch(void* const* d_in, const int* in_sizes, int n_in,
                              void* d_out, int out_size, void* d_ws, size_t ws_size,
                              hipStream_t stream) {
    const float* x    = (const float*)d_in[0];
    const int*   ei   = (const int*)d_in[1];
    const float* ew   = (const float*)d_in[2];
    const float* W1   = (const float*)d_in[3];
    const float* b1   = (const float*)d_in[4];
    const float* W2   = (const float*)d_in[5];
    const float* b2   = (const float*)d_in[6];
    const float* Wih  = (const float*)d_in[7];
    // d_in[8] = W_hh: unused (h0 = 0)
    const float* bih  = (const float*)d_in[9];
    const float* bhh  = (const float*)d_in[10];
    const float* Wreg = (const float*)d_in[11];
    const float* breg = (const float*)d_in[12];
    float* out = (float*)d_out;

    const int N = out_size;            // O = 1
    const int E = in_sizes[1] / 2;
    const int* row = ei;
    const int* col = ei + E;

    const int NB = (N + 255) / 256;    // 196 blocks over nodes
    const int Np = (N + 63) & ~63;
    const int Ep = (E + 63) & ~63;

    char* wsb = (char*)d_ws;
    size_t off = 0;
    float* dis    = (float*)(wsb + off); off += (size_t)Np * 4;
    int*   cnt    = (int*)  (wsb + off); off += (size_t)Np * 4;
    int*   rowptr = (int*)  (wsb + off); off += ((size_t)Np + 64) * 4;
    int*   cursor = (int*)  (wsb + off); off += (size_t)Np * 4;
    int*   bsum   = (int*)  (wsb + off); off += 256 * 4;
    int*   srcs   = (int*)  (wsb + off); off += (size_t)Ep * 4;
    float* vals   = (float*)(wsb + off); off += (size_t)Ep * 4;
    float* bufA   = (float*)(wsb + off); off += (size_t)N * 64 * 4;
    float* bufB   = (float*)(wsb + off); off += (size_t)N * 64 * 4;
    float* bufC   = (float*)(wsb + off); off += (size_t)N * 64 * 4;

    const int eb = (E + 255) / 256;
    const int gb = (N + 63) / 64;
    const int ab = (N + 3) / 4;

    // --- CSR-by-destination build + normalization (shared by both layers) ---
    hipMemsetAsync(dis, 0, (size_t)Np * sizeof(float), stream);
    hipMemsetAsync(cnt, 0, (size_t)Np * sizeof(int), stream);
    deg_count_k<<<eb, 256, 0, stream>>>(col, ew, dis, cnt, E, N);
    dis_k<<<NB, 256, 0, stream>>>(dis, N);
    scanA_k<<<NB, 256, 0, stream>>>(cnt, bsum, N);
    scanB_k<<<1, 256, 0, stream>>>(bsum, rowptr, NB, N);
    scanC_k<<<NB, 256, 0, stream>>>(cnt, bsum, rowptr, cursor, N);
    fill_k<<<eb, 256, 0, stream>>>(row, col, ew, dis, cursor, srcs, vals, E, N);

    // --- GCN layer 1 ---
    gemm64_k<128><<<gb, 256, 0, stream>>>(x, W1, bufA, N);
    aggregate_k<<<ab, 256, 0, stream>>>(bufA, rowptr, srcs, vals, dis, b1, bufB, N);

    // --- GCN layer 2 ---
    gemm64_k<64><<<gb, 256, 0, stream>>>(bufB, W2, bufC, N);
    aggregate_k<<<ab, 256, 0, stream>>>(bufC, rowptr, srcs, vals, dis, b2, bufA, N);

    // --- fused LSTM + regression head ---
    lstm_head_k<<<gb, 256, 0, stream>>>(bufA, Wih, bih, bhh, Wreg, breg, out, N);
}

// Round 4
// 313.761 us; speedup vs baseline: 5.1884x; 1.1173x over previous
//
#include <hip/hip_runtime.h>
#include <math.h>

// ---------------------------------------------------------------------------
// MandiFlowNet: GCNConv(128->64) -> ReLU -> GCNConv(64->64) -> ReLU ->
//               1-step LSTM (h0=c0=0) -> Linear(64->1)
// N=50000 nodes, E=800000 edges. All fp32.
//
// R2: CSR-by-destination build + gather aggregation (replaced 679us atomic
//     scatter).
// R3: lstm_head_k as register-blocked GEMM tile (76.8us -> off top-5).
// R4: deg_count_k (75us, 1.6M device-scope atomics) replaced by LDS-partial
//     histogram + coalesced reduce (atomic-free). deg/dis computed AFTER the
//     CSR fill via segment-sum; dis[src] folded into vals by a scale pass,
//     dis[dst] applied in aggregate. fill writes one packed 8B (src,val)
//     int2 instead of two 4B stores (halves scattered-write transactions).
// ---------------------------------------------------------------------------

#define QN 12544            // node-quarter size (LDS histogram; 4*QN >= N)
#define NPAD (4 * QN)       // 50176 padded node range
#define NSLICE 64           // edge slices for partial histograms

__device__ __forceinline__ float sigmoidf_(float x) {
    return 1.0f / (1.0f + expf(-x));
}

// --- stage 1: per-(slice,quarter) LDS histogram of col[], no global atomics
__global__ __launch_bounds__(256) void hist_k(const int* __restrict__ col,
                                              int* __restrict__ part, int E, int N) {
    __shared__ int hloc[QN];
    const int t = threadIdx.x;
    const int s = blockIdx.x >> 2;       // edge slice
    const int q = blockIdx.x & 3;        // node quarter
    const int lo = q * QN;
    for (int i = t; i < QN; i += 256) hloc[i] = 0;
    __syncthreads();
    const int per = (E + NSLICE - 1) / NSLICE;
    const int e0 = s * per, e1 = min(E, e0 + per);
    for (int e = e0 + t; e < e1; e += 256) {
        int c = col[e];
        unsigned rel = (unsigned)(c - lo);
        if (rel < (unsigned)QN && (unsigned)c < (unsigned)N)
            atomicAdd(&hloc[rel], 1);
    }
    __syncthreads();
    int* dst = part + (size_t)s * NPAD + lo;
    for (int i = t; i < QN; i += 256) dst[i] = hloc[i];
}

// --- stage 2: cnt[i] = sum over slices of part[s][i] (coalesced)
__global__ __launch_bounds__(256) void hreduce_k(const int* __restrict__ part,
                                                 int* __restrict__ cnt) {
    int i = blockIdx.x * 256 + threadIdx.x;
    if (i >= NPAD) return;
    const int* p = part + i;
    int s0 = 0, s1 = 0, s2 = 0, s3 = 0;
    for (int s = 0; s < NSLICE; s += 4) {
        s0 += p[(size_t)(s + 0) * NPAD];
        s1 += p[(size_t)(s + 1) * NPAD];
        s2 += p[(size_t)(s + 2) * NPAD];
        s3 += p[(size_t)(s + 3) * NPAD];
    }
    cnt[i] = (s0 + s1) + (s2 + s3);
}

// per-block sums of cnt -> bsum
__global__ __launch_bounds__(256) void scanA_k(const int* __restrict__ cnt,
                                               int* __restrict__ bsum, int N) {
    __shared__ int r[256];
    int t = threadIdx.x, i = blockIdx.x * 256 + t;
    r[t] = (i < N) ? cnt[i] : 0;
    __syncthreads();
#pragma unroll
    for (int off = 128; off > 0; off >>= 1) {
        if (t < off) r[t] += r[t + off];
        __syncthreads();
    }
    if (t == 0) bsum[blockIdx.x] = r[0];
}

// single-block exclusive scan of bsum[NB] (NB <= 256); writes rowptr[N] = E
__global__ __launch_bounds__(256) void scanB_k(int* __restrict__ bsum,
                                               int* __restrict__ rowptr, int NB, int N) {
    __shared__ int s[2][256];
    int t = threadIdx.x;
    int v = (t < NB) ? bsum[t] : 0;
    int pin = 0;
    s[0][t] = v;
    __syncthreads();
#pragma unroll
    for (int off = 1; off < 256; off <<= 1) {
        int x = s[pin][t];
        if (t >= off) x += s[pin][t - off];
        s[pin ^ 1][t] = x;
        pin ^= 1;
        __syncthreads();
    }
    int incl = s[pin][t];
    if (t < NB) bsum[t] = incl - v;     // exclusive block offset
    if (t == 255) rowptr[N] = incl;     // total = E
}

// in-block exclusive scan of cnt + block offset -> rowptr, cursor
__global__ __launch_bounds__(256) void scanC_k(const int* __restrict__ cnt,
                                               const int* __restrict__ bsum,
                                               int* __restrict__ rowptr,
                                               int* __restrict__ cursor, int N) {
    __shared__ int s[2][256];
    int t = threadIdx.x, i = blockIdx.x * 256 + t;
    int v = (i < N) ? cnt[i] : 0;
    int pin = 0;
    s[0][t] = v;
    __syncthreads();
#pragma unroll
    for (int off = 1; off < 256; off <<= 1) {
        int x = s[pin][t];
        if (t >= off) x += s[pin][t - off];
        s[pin ^ 1][t] = x;
        pin ^= 1;
        __syncthreads();
    }
    int excl = s[pin][t] - v + bsum[blockIdx.x];
    if (i < N) { rowptr[i] = excl; cursor[i] = excl; }
}

// fill CSR: packed (src, ew) pairs in destination-sorted order, one 8B store
__global__ __launch_bounds__(256) void fill_k(const int* __restrict__ row,
                                              const int* __restrict__ col,
                                              const float* __restrict__ ew,
                                              int* __restrict__ cursor,
                                              int2* __restrict__ pairs, int E, int N) {
    int e = blockIdx.x * 256 + threadIdx.x;
    if (e >= E) return;
    int r = row[e], c = col[e];
    if ((unsigned)c >= (unsigned)N) return;
    float w = ew[e];
    if ((unsigned)r >= (unsigned)N) { r = 0; w = 0.0f; }  // keep slot, zero weight
    int pos = __hip_atomic_fetch_add(&cursor[c], 1, __ATOMIC_RELAXED, __HIP_MEMORY_SCOPE_AGENT);
    pairs[pos] = make_int2(r, __float_as_int(w));
}

// deg from CSR segment-sum of ew; dis = rsqrt(deg + 1)
__global__ __launch_bounds__(256) void degsum_k(const int* __restrict__ rowptr,
                                                const int2* __restrict__ pairs,
                                                float* __restrict__ dis, int N) {
    int i = blockIdx.x * 256 + threadIdx.x;
    if (i >= N) return;
    int b = rowptr[i], en = rowptr[i + 1];
    float s = 0.0f;
    for (int e = b; e < en; ++e) s += __int_as_float(pairs[e].y);
    dis[i] = rsqrtf(s + 1.0f);
}

// vals[e] *= dis[src]  (coalesced RW over CSR positions; dis gather is L2-hit)
__global__ __launch_bounds__(256) void scale_k(int2* __restrict__ pairs,
                                               const float* __restrict__ dis, int E) {
    int e = blockIdx.x * 256 + threadIdx.x;
    if (e >= E) return;
    int2 p = pairs[e];
    p.y = __float_as_int(__int_as_float(p.y) * dis[p.x]);
    pairs[e] = p;
}

// out[c,:] = relu( dis[c]*( sum_e val_e*h[src_e,:] + dis[c]*h[c,:] ) + b )
// one wave per node, lane = feature; edge pairs loaded lane-parallel,
// broadcast via shfl; gathers 4-deep for memory-level parallelism.
__global__ __launch_bounds__(256) void aggregate_k(const float* __restrict__ h,
                                                   const int* __restrict__ rowptr,
                                                   const int2* __restrict__ pairs,
                                                   const float* __restrict__ dis,
                                                   const float* __restrict__ b,
                                                   float* __restrict__ out, int N) {
    const int t = threadIdx.x;
    const int lane = t & 63;
    const int node = blockIdx.x * 4 + (t >> 6);
    if (node >= N) return;

    const int beg = rowptr[node], end = rowptr[node + 1];
    float acc = 0.0f;
    for (int base = beg; base < end; base += 64) {
        int n = min(64, end - base);
        int src = 0; float val = 0.0f;
        if (lane < n) {
            int2 p = pairs[base + lane];
            src = p.x; val = __int_as_float(p.y);
        }
        int j = 0;
        for (; j + 4 <= n; j += 4) {
            int   s0 = __shfl(src, j),     s1 = __shfl(src, j + 1);
            int   s2 = __shfl(src, j + 2), s3 = __shfl(src, j + 3);
            float v0 = __shfl(val, j),     v1 = __shfl(val, j + 1);
            float v2 = __shfl(val, j + 2), v3 = __shfl(val, j + 3);
            float h0 = h[(size_t)s0 * 64 + lane];
            float h1 = h[(size_t)s1 * 64 + lane];
            float h2 = h[(size_t)s2 * 64 + lane];
            float h3 = h[(size_t)s3 * 64 + lane];
            acc = fmaf(h0, v0, acc);
            acc = fmaf(h1, v1, acc);
            acc = fmaf(h2, v2, acc);
            acc = fmaf(h3, v3, acc);
        }
        for (; j < n; ++j) {
            int s0 = __shfl(src, j);
            float v0 = __shfl(val, j);
            acc = fmaf(h[(size_t)s0 * 64 + lane], v0, acc);
        }
    }
    float d = dis[node];
    acc = fmaf(d, h[(size_t)node * 64 + lane], acc);   // self-loop (inner d)
    acc = fmaf(d, acc, b[lane]);                        // outer d + bias
    out[(size_t)node * 64 + lane] = fmaxf(acc, 0.0f);
}

// C[M,64] = A[M,K] @ W[K,64], fp32, LDS-tiled. Block = 64 rows, 256 threads,
// each thread a 4x4 micro-tile.
template <int K>
__global__ __launch_bounds__(256) void gemm64_k(const float* __restrict__ A,
                                                const float* __restrict__ W,
                                                float* __restrict__ C, int M) {
    __shared__ float xs[64][68];
    __shared__ float ws[K][64];
    const int t  = threadIdx.x;
    const int n0 = blockIdx.x * 64;

    for (int base = t * 4; base < K * 64; base += 1024)
        *(float4*)((float*)ws + base) = *(const float4*)(W + base);

    const int cg = t & 15, ng = t >> 4;
    const int col = cg * 4, nb = ng * 4;
    float acc[4][4];
#pragma unroll
    for (int i = 0; i < 4; ++i)
#pragma unroll
        for (int j = 0; j < 4; ++j) acc[i][j] = 0.0f;

    for (int k0 = 0; k0 < K; k0 += 64) {
        __syncthreads();
        for (int base = t * 4; base < 64 * 64; base += 1024) {
            int r = base >> 6, k = base & 63;
            int node = n0 + r;
            float4 v = make_float4(0.f, 0.f, 0.f, 0.f);
            if (node < M) v = *(const float4*)(A + (size_t)node * K + k0 + k);
            *(float4*)&xs[r][k] = v;
        }
        __syncthreads();
#pragma unroll 4
        for (int kk = 0; kk < 64; kk += 4) {
            float4 a[4];
#pragma unroll
            for (int i = 0; i < 4; ++i) a[i] = *(float4*)&xs[nb + i][kk];
#pragma unroll
            for (int j = 0; j < 4; ++j) {
                float4 bv = *(float4*)&ws[k0 + kk + j][col];
                float av[4];
                switch (j) {
                    case 0: av[0]=a[0].x; av[1]=a[1].x; av[2]=a[2].x; av[3]=a[3].x; break;
                    case 1: av[0]=a[0].y; av[1]=a[1].y; av[2]=a[2].y; av[3]=a[3].y; break;
                    case 2: av[0]=a[0].z; av[1]=a[1].z; av[2]=a[2].z; av[3]=a[3].z; break;
                    default:av[0]=a[0].w; av[1]=a[1].w; av[2]=a[2].w; av[3]=a[3].w; break;
                }
#pragma unroll
                for (int i = 0; i < 4; ++i) {
                    acc[i][0] = fmaf(av[i], bv.x, acc[i][0]);
                    acc[i][1] = fmaf(av[i], bv.y, acc[i][1]);
                    acc[i][2] = fmaf(av[i], bv.z, acc[i][2]);
                    acc[i][3] = fmaf(av[i], bv.w, acc[i][3]);
                }
            }
        }
    }
#pragma unroll
    for (int i = 0; i < 4; ++i) {
        int node = n0 + nb + i;
        if (node < M)
            *(float4*)(C + (size_t)node * 64 + col) =
                make_float4(acc[i][0], acc[i][1], acc[i][2], acc[i][3]);
    }
}

// Fused 1-step LSTM (h0=c0=0 => skip W_hh and f-gate) + regression head.
// Register-blocked GEMM tile: 64 nodes/block, thread = 4 nodes x 4 cols x
// {i,g,o}. hsT[k][node] transposed so 4 node-activations = one float4 read.
__global__ __launch_bounds__(256) void lstm_head_k(const float* __restrict__ h,
                                                   const float* __restrict__ Wih,
                                                   const float* __restrict__ bih,
                                                   const float* __restrict__ bhh,
                                                   const float* __restrict__ Wreg,
                                                   const float* __restrict__ breg,
                                                   float* __restrict__ out, int N) {
    __shared__ float wt[64 * 192];   // wt[k*192 + gateOff + j] = Wih[gBase+j][k]
    __shared__ float hsT[64 * 64];   // hsT[k*64 + r] = h[n0+r][k]
    const int t = threadIdx.x;
    const int n0 = blockIdx.x * 64;

    {
        const int j = t & 63, kq = (t >> 6) * 4;
#pragma unroll
        for (int gid = 0; gid < 3; ++gid) {
            const int gBase = (gid == 0) ? 0 : (gid == 1 ? 128 : 192);  // i,g,o
            const int gOff = gid * 64;
#pragma unroll
            for (int it = 0; it < 4; ++it) {
                int k0 = it * 16 + kq;
                float4 w = *(const float4*)(Wih + (size_t)(gBase + j) * 64 + k0);
                wt[(k0 + 0) * 192 + gOff + j] = w.x;
                wt[(k0 + 1) * 192 + gOff + j] = w.y;
                wt[(k0 + 2) * 192 + gOff + j] = w.z;
                wt[(k0 + 3) * 192 + gOff + j] = w.w;
            }
        }
    }
    {
        const int r = t & 63, kq = (t >> 6) * 4;
        const int node = n0 + r;
#pragma unroll
        for (int it = 0; it < 4; ++it) {
            int k0 = it * 16 + kq;
            float4 v = make_float4(0.f, 0.f, 0.f, 0.f);
            if (node < N) v = *(const float4*)(h + (size_t)node * 64 + k0);
            hsT[(k0 + 0) * 64 + r] = v.x;
            hsT[(k0 + 1) * 64 + r] = v.y;
            hsT[(k0 + 2) * 64 + r] = v.z;
            hsT[(k0 + 3) * 64 + r] = v.w;
        }
    }

    const int cg = t & 15, ng = t >> 4;
    const int col = cg * 4, nb = ng * 4;
    float4 bi4 = *(const float4*)(bih + col);
    float4 bg4 = *(const float4*)(bih + 128 + col);
    float4 bo4 = *(const float4*)(bih + 192 + col);
    {
        float4 h0 = *(const float4*)(bhh + col);
        float4 h1 = *(const float4*)(bhh + 128 + col);
        float4 h2 = *(const float4*)(bhh + 192 + col);
        bi4.x += h0.x; bi4.y += h0.y; bi4.z += h0.z; bi4.w += h0.w;
        bg4.x += h1.x; bg4.y += h1.y; bg4.z += h1.z; bg4.w += h1.w;
        bo4.x += h2.x; bo4.y += h2.y; bo4.z += h2.z; bo4.w += h2.w;
    }
    float4 wr4 = *(const float4*)(Wreg + col);
    const float br = breg[0];

    __syncthreads();

    float ai[4][4], ag[4][4], ao[4][4];
#pragma unroll
    for (int i = 0; i < 4; ++i)
#pragma unroll
        for (int j = 0; j < 4; ++j) { ai[i][j] = 0.f; ag[i][j] = 0.f; ao[i][j] = 0.f; }

#pragma unroll 4
    for (int k = 0; k < 64; ++k) {
        float4 a  = *(float4*)&hsT[k * 64 + nb];
        float4 wi = *(float4*)&wt[k * 192 + col];
        float4 wg = *(float4*)&wt[k * 192 + 64 + col];
        float4 wo = *(float4*)&wt[k * 192 + 128 + col];
        const float av[4] = {a.x, a.y, a.z, a.w};
#pragma unroll
        for (int i = 0; i < 4; ++i) {
            ai[i][0] = fmaf(av[i], wi.x, ai[i][0]);
            ai[i][1] = fmaf(av[i], wi.y, ai[i][1]);
            ai[i][2] = fmaf(av[i], wi.z, ai[i][2]);
            ai[i][3] = fmaf(av[i], wi.w, ai[i][3]);
            ag[i][0] = fmaf(av[i], wg.x, ag[i][0]);
            ag[i][1] = fmaf(av[i], wg.y, ag[i][1]);
            ag[i][2] = fmaf(av[i], wg.z, ag[i][2]);
            ag[i][3] = fmaf(av[i], wg.w, ag[i][3]);
            ao[i][0] = fmaf(av[i], wo.x, ao[i][0]);
            ao[i][1] = fmaf(av[i], wo.y, ao[i][1]);
            ao[i][2] = fmaf(av[i], wo.z, ao[i][2]);
            ao[i][3] = fmaf(av[i], wo.w, ao[i][3]);
        }
    }

    const float bia[4] = {bi4.x, bi4.y, bi4.z, bi4.w};
    const float bga[4] = {bg4.x, bg4.y, bg4.z, bg4.w};
    const float boa[4] = {bo4.x, bo4.y, bo4.z, bo4.w};
    const float wra[4] = {wr4.x, wr4.y, wr4.z, wr4.w};
    float res[4];
#pragma unroll
    for (int i = 0; i < 4; ++i) {
        float s = 0.f;
#pragma unroll
        for (int j = 0; j < 4; ++j) {
            float gi = ai[i][j] + bia[j];
            float gg = ag[i][j] + bga[j];
            float go = ao[i][j] + boa[j];
            float cc = sigmoidf_(gi) * tanhf(gg);
            float hn = sigmoidf_(go) * tanhf(cc);
            s = fmaf(hn, wra[j], s);
        }
        res[i] = s;
    }
#pragma unroll
    for (int off = 8; off > 0; off >>= 1) {
#pragma unroll
        for (int i = 0; i < 4; ++i) res[i] += __shfl_down(res[i], off);
    }
    if (cg == 0) {
#pragma unroll
        for (int i = 0; i < 4; ++i) {
            int node = n0 + nb + i;
            if (node < N) out[node] = res[i] + br;
        }
    }
}

extern "C" void kernel_launch(void* const* d_in, const int* in_sizes, int n_in,
                              void* d_out, int out_size, void* d_ws, size_t ws_size,
                              hipStream_t stream) {
    const float* x    = (const float*)d_in[0];
    const int*   ei   = (const int*)d_in[1];
    const float* ew   = (const float*)d_in[2];
    const float* W1   = (const float*)d_in[3];
    const float* b1   = (const float*)d_in[4];
    const float* W2   = (const float*)d_in[5];
    const float* b2   = (const float*)d_in[6];
    const float* Wih  = (const float*)d_in[7];
    // d_in[8] = W_hh: unused (h0 = 0)
    const float* bih  = (const float*)d_in[9];
    const float* bhh  = (const float*)d_in[10];
    const float* Wreg = (const float*)d_in[11];
    const float* breg = (const float*)d_in[12];
    float* out = (float*)d_out;

    const int N = out_size;            // O = 1  (N <= NPAD assumed)
    const int E = in_sizes[1] / 2;
    const int* row = ei;
    const int* col = ei + E;

    const int NB = (N + 255) / 256;

    char* wsb = (char*)d_ws;
    size_t off = 0;
    // part (64 slices x NPAD ints) — dead after hreduce_k; bufA aliases it
    int*   part   = (int*)  (wsb + off);
    float* bufA   = (float*)(wsb + off); off += (size_t)NSLICE * NPAD * 4;
    int2*  pairs  = (int2*) (wsb + off); off += (size_t)E * 8;
    float* dis    = (float*)(wsb + off); off += (size_t)NPAD * 4;
    int*   cnt    = (int*)  (wsb + off); off += (size_t)NPAD * 4;
    int*   rowptr = (int*)  (wsb + off); off += ((size_t)NPAD + 64) * 4;
    int*   cursor = (int*)  (wsb + off); off += (size_t)NPAD * 4;
    int*   bsum   = (int*)  (wsb + off); off += 1024;
    float* bufB   = (float*)(wsb + off); off += (size_t)N * 64 * 4;
    float* bufC   = (float*)(wsb + off); off += (size_t)N * 64 * 4;

    const int eb = (E + 255) / 256;
    const int gb = (N + 63) / 64;
    const int ab = (N + 3) / 4;

    // --- CSR-by-destination build (atomic-free histogram) ---
    hist_k<<<NSLICE * 4, 256, 0, stream>>>(col, part, E, N);
    hreduce_k<<<NPAD / 256, 256, 0, stream>>>(part, cnt);
    scanA_k<<<NB, 256, 0, stream>>>(cnt, bsum, N);
    scanB_k<<<1, 256, 0, stream>>>(bsum, rowptr, NB, N);
    scanC_k<<<NB, 256, 0, stream>>>(cnt, bsum, rowptr, cursor, N);
    fill_k<<<eb, 256, 0, stream>>>(row, col, ew, cursor, pairs, E, N);
    degsum_k<<<NB, 256, 0, stream>>>(rowptr, pairs, dis, N);
    scale_k<<<eb, 256, 0, stream>>>(pairs, dis, E);

    // --- GCN layer 1 ---  (bufA aliases part; part dead after hreduce_k)
    gemm64_k<128><<<gb, 256, 0, stream>>>(x, W1, bufA, N);
    aggregate_k<<<ab, 256, 0, stream>>>(bufA, rowptr, pairs, dis, b1, bufB, N);

    // --- GCN layer 2 ---
    gemm64_k<64><<<gb, 256, 0, stream>>>(bufB, W2, bufC, N);
    aggregate_k<<<ab, 256, 0, stream>>>(bufC, rowptr, pairs, dis, b2, bufA, N);

    // --- fused LSTM + regression head ---
    lstm_head_k<<<gb, 256, 0, stream>>>(bufA, Wih, bih, bhh, Wreg, breg, out, N);
}

// Round 5
// 311.248 us; speedup vs baseline: 5.2303x; 1.0081x over previous
//
#include <hip/hip_runtime.h>
#include <math.h>

// ---------------------------------------------------------------------------
// MandiFlowNet: GCNConv(128->64) -> ReLU -> GCNConv(64->64) -> ReLU ->
//               1-step LSTM (h0=c0=0) -> Linear(64->1)
// N=50000 nodes, E=800000 edges. All fp32.
//
// R2: CSR-by-destination + gather aggregation (replaced 679us atomic scatter).
// R3: lstm_head_k as register-blocked GEMM tile (76.8us -> ~12us).
// R4: atomic-free histogram; packed 8B (src,val) pairs (deg_count 75us gone).
// R5: fill_k made atomic-free via slice-prefix stable counting sort:
//     hist_k also accumulates float Sum(ew) partials (weighted degree),
//     prefix_k produces per-(slice,node) offsets + cnt + dis in one pass,
//     fill_k places edges via LDS cursors (zero global atomics) and writes
//     fully-normalized vals (degsum_k / scale_k deleted).
// ---------------------------------------------------------------------------

#define QN 12544            // node-quarter size (LDS histogram; 4*QN >= N)
#define NPAD (4 * QN)       // 50176 padded node range
#define NSLICE 64           // edge slices; NSLICE*4 = 256 blocks = 256 CUs

__device__ __forceinline__ float sigmoidf_(float x) {
    return 1.0f / (1.0f + expf(-x));
}

// --- stage 1: per-(slice,quarter) LDS histogram of col[]: counts + Sum(ew)
__global__ __launch_bounds__(256) void hist_k(const int* __restrict__ col,
                                              const float* __restrict__ ew,
                                              int* __restrict__ part_i,
                                              float* __restrict__ part_f, int E, int N) {
    __shared__ int   hc[QN];
    __shared__ float hw[QN];
    const int t = threadIdx.x;
    const int s = blockIdx.x >> 2;       // edge slice
    const int q = blockIdx.x & 3;        // node quarter
    const int lo = q * QN;
    for (int i = t; i < QN; i += 256) { hc[i] = 0; hw[i] = 0.0f; }
    __syncthreads();
    const int per = (E + NSLICE - 1) / NSLICE;
    const int e0 = s * per, e1 = min(E, e0 + per);
    for (int e = e0 + t; e < e1; e += 256) {
        int c = col[e];
        unsigned rel = (unsigned)(c - lo);
        if (rel < (unsigned)QN && (unsigned)c < (unsigned)N) {
            atomicAdd(&hc[rel], 1);
            atomicAdd(&hw[rel], ew[e]);
        }
    }
    __syncthreads();
    int*   di = part_i + (size_t)s * NPAD + lo;
    float* df = part_f + (size_t)s * NPAD + lo;
    for (int i = t; i < QN; i += 256) { di[i] = hc[i]; df[i] = hw[i]; }
}

// --- stage 2: coff[s][i] = prefix over slices; cnt[i] = total count;
//              dis[i] = rsqrt(weighted_deg + 1). All accesses coalesced.
__global__ __launch_bounds__(256) void prefix_k(const int* __restrict__ part_i,
                                                const float* __restrict__ part_f,
                                                int* __restrict__ coff,
                                                int* __restrict__ cnt,
                                                float* __restrict__ dis) {
    int i = blockIdx.x * 256 + threadIdx.x;   // grid = NPAD/256, NPAD%256==0
    int acc = 0; float wacc = 0.0f;
    for (int s = 0; s < NSLICE; ++s) {
        size_t idx = (size_t)s * NPAD + i;
        coff[idx] = acc;
        acc  += part_i[idx];
        wacc += part_f[idx];
    }
    cnt[i] = acc;
    dis[i] = rsqrtf(wacc + 1.0f);
}

// per-block sums of cnt -> bsum
__global__ __launch_bounds__(256) void scanA_k(const int* __restrict__ cnt,
                                               int* __restrict__ bsum, int N) {
    __shared__ int r[256];
    int t = threadIdx.x, i = blockIdx.x * 256 + t;
    r[t] = (i < N) ? cnt[i] : 0;
    __syncthreads();
#pragma unroll
    for (int off = 128; off > 0; off >>= 1) {
        if (t < off) r[t] += r[t + off];
        __syncthreads();
    }
    if (t == 0) bsum[blockIdx.x] = r[0];
}

// single-block exclusive scan of bsum[NB] (NB <= 256); writes rowptr[N] = E
__global__ __launch_bounds__(256) void scanB_k(int* __restrict__ bsum,
                                               int* __restrict__ rowptr, int NB, int N) {
    __shared__ int s[2][256];
    int t = threadIdx.x;
    int v = (t < NB) ? bsum[t] : 0;
    int pin = 0;
    s[0][t] = v;
    __syncthreads();
#pragma unroll
    for (int off = 1; off < 256; off <<= 1) {
        int x = s[pin][t];
        if (t >= off) x += s[pin][t - off];
        s[pin ^ 1][t] = x;
        pin ^= 1;
        __syncthreads();
    }
    int incl = s[pin][t];
    if (t < NB) bsum[t] = incl - v;     // exclusive block offset
    if (t == 255) rowptr[N] = incl;     // total = E
}

// in-block exclusive scan of cnt + block offset -> rowptr
__global__ __launch_bounds__(256) void scanC_k(const int* __restrict__ cnt,
                                               const int* __restrict__ bsum,
                                               int* __restrict__ rowptr, int N) {
    __shared__ int s[2][256];
    int t = threadIdx.x, i = blockIdx.x * 256 + t;
    int v = (i < N) ? cnt[i] : 0;
    int pin = 0;
    s[0][t] = v;
    __syncthreads();
#pragma unroll
    for (int off = 1; off < 256; off <<= 1) {
        int x = s[pin][t];
        if (t >= off) x += s[pin][t - off];
        s[pin ^ 1][t] = x;
        pin ^= 1;
        __syncthreads();
    }
    int excl = s[pin][t] - v + bsum[blockIdx.x];
    if (i < N) rowptr[i] = excl;
}

// --- stage 3: stable fill via LDS cursors, ZERO global atomics.
// Block (s,q): cursor[rel] = rowptr[node] + coff[s][node]; edges of slice s
// with dst in quarter q are placed via LDS atomicAdd (contention ~0.25/node).
// vals carry the full norm  ew * dis[src] * dis[dst].
__global__ __launch_bounds__(256) void fill_k(const int* __restrict__ row,
                                              const int* __restrict__ col,
                                              const float* __restrict__ ew,
                                              const int* __restrict__ rowptr,
                                              const int* __restrict__ coff,
                                              const float* __restrict__ dis,
                                              int2* __restrict__ pairs, int E, int N) {
    __shared__ int lcur[QN];
    const int t = threadIdx.x;
    const int s = blockIdx.x >> 2;
    const int q = blockIdx.x & 3;
    const int lo = q * QN;
    const int* cof = coff + (size_t)s * NPAD + lo;
    const int* rp  = rowptr + lo;
    for (int i = t; i < QN; i += 256) lcur[i] = rp[i] + cof[i];
    __syncthreads();
    const int per = (E + NSLICE - 1) / NSLICE;
    const int e0 = s * per, e1 = min(E, e0 + per);
    for (int e = e0 + t; e < e1; e += 256) {
        int c = col[e];
        unsigned rel = (unsigned)(c - lo);
        if (rel < (unsigned)QN && (unsigned)c < (unsigned)N) {
            int r = row[e];
            float w = ew[e];
            if ((unsigned)r >= (unsigned)N) { r = 0; w = 0.0f; }  // keep slot
            float nv = w * dis[r] * dis[c];
            int pos = atomicAdd(&lcur[rel], 1);
            pairs[pos] = make_int2(r, __float_as_int(nv));
        }
    }
}

// out[c,:] = relu( sum_e val_e*h[src_e,:] + dis[c]^2*h[c,:] + b )
// one wave per node, lane = feature; edge pairs loaded lane-parallel,
// broadcast via shfl; gathers 4-deep for memory-level parallelism.
__global__ __launch_bounds__(256) void aggregate_k(const float* __restrict__ h,
                                                   const int* __restrict__ rowptr,
                                                   const int2* __restrict__ pairs,
                                                   const float* __restrict__ dis,
                                                   const float* __restrict__ b,
                                                   float* __restrict__ out, int N) {
    const int t = threadIdx.x;
    const int lane = t & 63;
    const int node = blockIdx.x * 4 + (t >> 6);
    if (node >= N) return;

    const int beg = rowptr[node], end = rowptr[node + 1];
    float acc = 0.0f;
    for (int base = beg; base < end; base += 64) {
        int n = min(64, end - base);
        int src = 0; float val = 0.0f;
        if (lane < n) {
            int2 p = pairs[base + lane];
            src = p.x; val = __int_as_float(p.y);
        }
        int j = 0;
        for (; j + 4 <= n; j += 4) {
            int   s0 = __shfl(src, j),     s1 = __shfl(src, j + 1);
            int   s2 = __shfl(src, j + 2), s3 = __shfl(src, j + 3);
            float v0 = __shfl(val, j),     v1 = __shfl(val, j + 1);
            float v2 = __shfl(val, j + 2), v3 = __shfl(val, j + 3);
            float h0 = h[(size_t)s0 * 64 + lane];
            float h1 = h[(size_t)s1 * 64 + lane];
            float h2 = h[(size_t)s2 * 64 + lane];
            float h3 = h[(size_t)s3 * 64 + lane];
            acc = fmaf(h0, v0, acc);
            acc = fmaf(h1, v1, acc);
            acc = fmaf(h2, v2, acc);
            acc = fmaf(h3, v3, acc);
        }
        for (; j < n; ++j) {
            int s0 = __shfl(src, j);
            float v0 = __shfl(val, j);
            acc = fmaf(h[(size_t)s0 * 64 + lane], v0, acc);
        }
    }
    float d = dis[node];
    acc = fmaf(d * d, h[(size_t)node * 64 + lane], acc) + b[lane];
    out[(size_t)node * 64 + lane] = fmaxf(acc, 0.0f);
}

// C[M,64] = A[M,K] @ W[K,64], fp32, LDS-tiled. Block = 64 rows, 256 threads,
// each thread a 4x4 micro-tile.
template <int K>
__global__ __launch_bounds__(256) void gemm64_k(const float* __restrict__ A,
                                                const float* __restrict__ W,
                                                float* __restrict__ C, int M) {
    __shared__ float xs[64][68];
    __shared__ float ws[K][64];
    const int t  = threadIdx.x;
    const int n0 = blockIdx.x * 64;

    for (int base = t * 4; base < K * 64; base += 1024)
        *(float4*)((float*)ws + base) = *(const float4*)(W + base);

    const int cg = t & 15, ng = t >> 4;
    const int col = cg * 4, nb = ng * 4;
    float acc[4][4];
#pragma unroll
    for (int i = 0; i < 4; ++i)
#pragma unroll
        for (int j = 0; j < 4; ++j) acc[i][j] = 0.0f;

    for (int k0 = 0; k0 < K; k0 += 64) {
        __syncthreads();
        for (int base = t * 4; base < 64 * 64; base += 1024) {
            int r = base >> 6, k = base & 63;
            int node = n0 + r;
            float4 v = make_float4(0.f, 0.f, 0.f, 0.f);
            if (node < M) v = *(const float4*)(A + (size_t)node * K + k0 + k);
            *(float4*)&xs[r][k] = v;
        }
        __syncthreads();
#pragma unroll 4
        for (int kk = 0; kk < 64; kk += 4) {
            float4 a[4];
#pragma unroll
            for (int i = 0; i < 4; ++i) a[i] = *(float4*)&xs[nb + i][kk];
#pragma unroll
            for (int j = 0; j < 4; ++j) {
                float4 bv = *(float4*)&ws[k0 + kk + j][col];
                float av[4];
                switch (j) {
                    case 0: av[0]=a[0].x; av[1]=a[1].x; av[2]=a[2].x; av[3]=a[3].x; break;
                    case 1: av[0]=a[0].y; av[1]=a[1].y; av[2]=a[2].y; av[3]=a[3].y; break;
                    case 2: av[0]=a[0].z; av[1]=a[1].z; av[2]=a[2].z; av[3]=a[3].z; break;
                    default:av[0]=a[0].w; av[1]=a[1].w; av[2]=a[2].w; av[3]=a[3].w; break;
                }
#pragma unroll
                for (int i = 0; i < 4; ++i) {
                    acc[i][0] = fmaf(av[i], bv.x, acc[i][0]);
                    acc[i][1] = fmaf(av[i], bv.y, acc[i][1]);
                    acc[i][2] = fmaf(av[i], bv.z, acc[i][2]);
                    acc[i][3] = fmaf(av[i], bv.w, acc[i][3]);
                }
            }
        }
    }
#pragma unroll
    for (int i = 0; i < 4; ++i) {
        int node = n0 + nb + i;
        if (node < M)
            *(float4*)(C + (size_t)node * 64 + col) =
                make_float4(acc[i][0], acc[i][1], acc[i][2], acc[i][3]);
    }
}

// Fused 1-step LSTM (h0=c0=0 => skip W_hh and f-gate) + regression head.
// Register-blocked GEMM tile: 64 nodes/block, thread = 4 nodes x 4 cols x
// {i,g,o}. hsT[k][node] transposed so 4 node-activations = one float4 read.
__global__ __launch_bounds__(256) void lstm_head_k(const float* __restrict__ h,
                                                   const float* __restrict__ Wih,
                                                   const float* __restrict__ bih,
                                                   const float* __restrict__ bhh,
                                                   const float* __restrict__ Wreg,
                                                   const float* __restrict__ breg,
                                                   float* __restrict__ out, int N) {
    __shared__ float wt[64 * 192];   // wt[k*192 + gateOff + j] = Wih[gBase+j][k]
    __shared__ float hsT[64 * 64];   // hsT[k*64 + r] = h[n0+r][k]
    const int t = threadIdx.x;
    const int n0 = blockIdx.x * 64;

    {
        const int j = t & 63, kq = (t >> 6) * 4;
#pragma unroll
        for (int gid = 0; gid < 3; ++gid) {
            const int gBase = (gid == 0) ? 0 : (gid == 1 ? 128 : 192);  // i,g,o
            const int gOff = gid * 64;
#pragma unroll
            for (int it = 0; it < 4; ++it) {
                int k0 = it * 16 + kq;
                float4 w = *(const float4*)(Wih + (size_t)(gBase + j) * 64 + k0);
                wt[(k0 + 0) * 192 + gOff + j] = w.x;
                wt[(k0 + 1) * 192 + gOff + j] = w.y;
                wt[(k0 + 2) * 192 + gOff + j] = w.z;
                wt[(k0 + 3) * 192 + gOff + j] = w.w;
            }
        }
    }
    {
        const int r = t & 63, kq = (t >> 6) * 4;
        const int node = n0 + r;
#pragma unroll
        for (int it = 0; it < 4; ++it) {
            int k0 = it * 16 + kq;
            float4 v = make_float4(0.f, 0.f, 0.f, 0.f);
            if (node < N) v = *(const float4*)(h + (size_t)node * 64 + k0);
            hsT[(k0 + 0) * 64 + r] = v.x;
            hsT[(k0 + 1) * 64 + r] = v.y;
            hsT[(k0 + 2) * 64 + r] = v.z;
            hsT[(k0 + 3) * 64 + r] = v.w;
        }
    }

    const int cg = t & 15, ng = t >> 4;
    const int col = cg * 4, nb = ng * 4;
    float4 bi4 = *(const float4*)(bih + col);
    float4 bg4 = *(const float4*)(bih + 128 + col);
    float4 bo4 = *(const float4*)(bih + 192 + col);
    {
        float4 h0 = *(const float4*)(bhh + col);
        float4 h1 = *(const float4*)(bhh + 128 + col);
        float4 h2 = *(const float4*)(bhh + 192 + col);
        bi4.x += h0.x; bi4.y += h0.y; bi4.z += h0.z; bi4.w += h0.w;
        bg4.x += h1.x; bg4.y += h1.y; bg4.z += h1.z; bg4.w += h1.w;
        bo4.x += h2.x; bo4.y += h2.y; bo4.z += h2.z; bo4.w += h2.w;
    }
    float4 wr4 = *(const float4*)(Wreg + col);
    const float br = breg[0];

    __syncthreads();

    float ai[4][4], ag[4][4], ao[4][4];
#pragma unroll
    for (int i = 0; i < 4; ++i)
#pragma unroll
        for (int j = 0; j < 4; ++j) { ai[i][j] = 0.f; ag[i][j] = 0.f; ao[i][j] = 0.f; }

#pragma unroll 4
    for (int k = 0; k < 64; ++k) {
        float4 a  = *(float4*)&hsT[k * 64 + nb];
        float4 wi = *(float4*)&wt[k * 192 + col];
        float4 wg = *(float4*)&wt[k * 192 + 64 + col];
        float4 wo = *(float4*)&wt[k * 192 + 128 + col];
        const float av[4] = {a.x, a.y, a.z, a.w};
#pragma unroll
        for (int i = 0; i < 4; ++i) {
            ai[i][0] = fmaf(av[i], wi.x, ai[i][0]);
            ai[i][1] = fmaf(av[i], wi.y, ai[i][1]);
            ai[i][2] = fmaf(av[i], wi.z, ai[i][2]);
            ai[i][3] = fmaf(av[i], wi.w, ai[i][3]);
            ag[i][0] = fmaf(av[i], wg.x, ag[i][0]);
            ag[i][1] = fmaf(av[i], wg.y, ag[i][1]);
            ag[i][2] = fmaf(av[i], wg.z, ag[i][2]);
            ag[i][3] = fmaf(av[i], wg.w, ag[i][3]);
            ao[i][0] = fmaf(av[i], wo.x, ao[i][0]);
            ao[i][1] = fmaf(av[i], wo.y, ao[i][1]);
            ao[i][2] = fmaf(av[i], wo.z, ao[i][2]);
            ao[i][3] = fmaf(av[i], wo.w, ao[i][3]);
        }
    }

    const float bia[4] = {bi4.x, bi4.y, bi4.z, bi4.w};
    const float bga[4] = {bg4.x, bg4.y, bg4.z, bg4.w};
    const float boa[4] = {bo4.x, bo4.y, bo4.z, bo4.w};
    const float wra[4] = {wr4.x, wr4.y, wr4.z, wr4.w};
    float res[4];
#pragma unroll
    for (int i = 0; i < 4; ++i) {
        float s = 0.f;
#pragma unroll
        for (int j = 0; j < 4; ++j) {
            float gi = ai[i][j] + bia[j];
            float gg = ag[i][j] + bga[j];
            float go = ao[i][j] + boa[j];
            float cc = sigmoidf_(gi) * tanhf(gg);
            float hn = sigmoidf_(go) * tanhf(cc);
            s = fmaf(hn, wra[j], s);
        }
        res[i] = s;
    }
#pragma unroll
    for (int off = 8; off > 0; off >>= 1) {
#pragma unroll
        for (int i = 0; i < 4; ++i) res[i] += __shfl_down(res[i], off);
    }
    if (cg == 0) {
#pragma unroll
        for (int i = 0; i < 4; ++i) {
            int node = n0 + nb + i;
            if (node < N) out[node] = res[i] + br;
        }
    }
}

extern "C" void kernel_launch(void* const* d_in, const int* in_sizes, int n_in,
                              void* d_out, int out_size, void* d_ws, size_t ws_size,
                              hipStream_t stream) {
    const float* x    = (const float*)d_in[0];
    const int*   ei   = (const int*)d_in[1];
    const float* ew   = (const float*)d_in[2];
    const float* W1   = (const float*)d_in[3];
    const float* b1   = (const float*)d_in[4];
    const float* W2   = (const float*)d_in[5];
    const float* b2   = (const float*)d_in[6];
    const float* Wih  = (const float*)d_in[7];
    // d_in[8] = W_hh: unused (h0 = 0)
    const float* bih  = (const float*)d_in[9];
    const float* bhh  = (const float*)d_in[10];
    const float* Wreg = (const float*)d_in[11];
    const float* breg = (const float*)d_in[12];
    float* out = (float*)d_out;

    const int N = out_size;            // O = 1  (N <= NPAD assumed)
    const int E = in_sizes[1] / 2;
    const int* row = ei;
    const int* col = ei + E;

    const int NB = (N + 255) / 256;

    // region size shared by {part_i, part_f, coff} and {bufA, bufB, bufC}
    const size_t REG = ((size_t)NSLICE * NPAD > (size_t)N * 64 ? (size_t)NSLICE * NPAD
                                                               : (size_t)N * 64) * 4;
    char* wsb = (char*)d_ws;
    size_t off = 0;
    // stream-order aliasing (each pre-pass buffer dead before its GEMM writer):
    //   part_i -> bufA (gemm1 out), part_f -> bufB (agg1 out), coff -> bufC (gemm2 out)
    int*   part_i = (int*)  (wsb + off);
    float* bufA   = (float*)(wsb + off); off += REG;
    float* part_f = (float*)(wsb + off);
    float* bufB   = (float*)(wsb + off); off += REG;
    int*   coff   = (int*)  (wsb + off);
    float* bufC   = (float*)(wsb + off); off += REG;
    int2*  pairs  = (int2*) (wsb + off); off += (size_t)E * 8;
    float* dis    = (float*)(wsb + off); off += (size_t)NPAD * 4;
    int*   cnt    = (int*)  (wsb + off); off += (size_t)NPAD * 4;
    int*   rowptr = (int*)  (wsb + off); off += ((size_t)NPAD + 64) * 4;
    int*   bsum   = (int*)  (wsb + off); off += 1024;

    const int gb = (N + 63) / 64;
    const int ab = (N + 3) / 4;

    // --- CSR-by-destination build (fully atomic-free in global memory) ---
    hist_k<<<NSLICE * 4, 256, 0, stream>>>(col, ew, part_i, part_f, E, N);
    prefix_k<<<NPAD / 256, 256, 0, stream>>>(part_i, part_f, coff, cnt, dis);
    scanA_k<<<NB, 256, 0, stream>>>(cnt, bsum, N);
    scanB_k<<<1, 256, 0, stream>>>(bsum, rowptr, NB, N);
    scanC_k<<<NB, 256, 0, stream>>>(cnt, bsum, rowptr, N);
    fill_k<<<NSLICE * 4, 256, 0, stream>>>(row, col, ew, rowptr, coff, dis, pairs, E, N);

    // --- GCN layer 1 ---  (bufA aliases part_i: dead after prefix_k)
    gemm64_k<128><<<gb, 256, 0, stream>>>(x, W1, bufA, N);
    aggregate_k<<<ab, 256, 0, stream>>>(bufA, rowptr, pairs, dis, b1, bufB, N);

    // --- GCN layer 2 ---  (bufC aliases coff: dead after fill_k)
    gemm64_k<64><<<gb, 256, 0, stream>>>(bufB, W2, bufC, N);
    aggregate_k<<<ab, 256, 0, stream>>>(bufC, rowptr, pairs, dis, b2, bufA, N);

    // --- fused LSTM + regression head ---
    lstm_head_k<<<gb, 256, 0, stream>>>(bufA, Wih, bih, bhh, Wreg, breg, out, N);
}

// Round 6
// 280.312 us; speedup vs baseline: 5.8075x; 1.1104x over previous
//
#include <hip/hip_runtime.h>
#include <math.h>

// ---------------------------------------------------------------------------
// MandiFlowNet: GCNConv(128->64) -> ReLU -> GCNConv(64->64) -> ReLU ->
//               1-step LSTM (h0=c0=0) -> Linear(64->1)
// N=50000 nodes, E=800000 edges. All fp32.
//
// R2: CSR-by-destination + gather aggregation (replaced 679us atomic scatter).
// R3: lstm_head_k as register-blocked GEMM tile (76.8us -> ~12us).
// R4: atomic-free histogram; packed 8B (src,val) pairs.
// R5: atomic-free stable fill via slice-prefix counting sort (58->50us, but
//     latency-bound: 1 block/CU, VALUBusy 3.7%).
// R6: fill/hist parallelism x8: NSLICE 64->128, quarters->octants (QN=6272,
//     LDS 25KB -> 4 blocks/CU), u16 part/coff to keep workspace flat,
//     4-deep edge batching. deg via post-fill segment-sum (degsum_k) +
//     scale_k (dis[src] into vals; dis[dst] in aggregate epilogue).
//     aggregate_k: 2 adjacent nodes per wave interleaved (8 gathers in
//     flight), grid 12.5k -> 6.25k blocks.
// ---------------------------------------------------------------------------

#define QN 6272             // node-octant size (LDS cursor/hist; 8*QN >= N)
#define NOCT 8
#define NPAD (NOCT * QN)    // 50176 padded node range
#define NSLICE 128          // edge slices; NSLICE*NOCT = 1024 blocks

__device__ __forceinline__ float sigmoidf_(float x) {
    return 1.0f / (1.0f + expf(-x));
}

// --- stage 1: per-(slice,octant) LDS histogram of col[] counts
__global__ __launch_bounds__(256) void hist_k(const int* __restrict__ col,
                                              unsigned short* __restrict__ part,
                                              int E, int N) {
    __shared__ int hc[QN];
    const int t = threadIdx.x;
    const int s = blockIdx.x >> 3;       // edge slice
    const int q = blockIdx.x & 7;        // node octant
    const int lo = q * QN;
    for (int i = t; i < QN; i += 256) hc[i] = 0;
    __syncthreads();
    const int per = (E + NSLICE - 1) / NSLICE;
    const int e0 = s * per, e1 = min(E, e0 + per);
    int e = e0 + t;
    for (; e + 768 < e1; e += 1024) {    // 4-deep batched col loads
        int c0 = col[e], c1 = col[e + 256], c2 = col[e + 512], c3 = col[e + 768];
        unsigned r0 = (unsigned)(c0 - lo), r1 = (unsigned)(c1 - lo);
        unsigned r2 = (unsigned)(c2 - lo), r3 = (unsigned)(c3 - lo);
        if (r0 < (unsigned)QN && (unsigned)c0 < (unsigned)N) atomicAdd(&hc[r0], 1);
        if (r1 < (unsigned)QN && (unsigned)c1 < (unsigned)N) atomicAdd(&hc[r1], 1);
        if (r2 < (unsigned)QN && (unsigned)c2 < (unsigned)N) atomicAdd(&hc[r2], 1);
        if (r3 < (unsigned)QN && (unsigned)c3 < (unsigned)N) atomicAdd(&hc[r3], 1);
    }
    for (; e < e1; e += 256) {
        int c = col[e];
        unsigned rel = (unsigned)(c - lo);
        if (rel < (unsigned)QN && (unsigned)c < (unsigned)N) atomicAdd(&hc[rel], 1);
    }
    __syncthreads();
    unsigned short* dst = part + (size_t)s * NPAD + lo;
    for (int i = t; i < QN; i += 256) dst[i] = (unsigned short)hc[i];
}

// --- stage 2: coff[s][i] = prefix over slices (u16); cnt[i] = total.
// u16 is safe: coff <= degree(i), and uniform-random E=16*N has max deg ~60.
__global__ __launch_bounds__(256) void prefix_k(const unsigned short* __restrict__ part,
                                                unsigned short* __restrict__ coff,
                                                int* __restrict__ cnt) {
    int i = blockIdx.x * 256 + threadIdx.x;   // grid = NPAD/256
    int acc = 0;
    for (int s = 0; s < NSLICE; ++s) {
        size_t idx = (size_t)s * NPAD + i;
        coff[idx] = (unsigned short)acc;
        acc += part[idx];
    }
    cnt[i] = acc;
}

// per-block sums of cnt -> bsum
__global__ __launch_bounds__(256) void scanA_k(const int* __restrict__ cnt,
                                               int* __restrict__ bsum, int N) {
    __shared__ int r[256];
    int t = threadIdx.x, i = blockIdx.x * 256 + t;
    r[t] = (i < N) ? cnt[i] : 0;
    __syncthreads();
#pragma unroll
    for (int off = 128; off > 0; off >>= 1) {
        if (t < off) r[t] += r[t + off];
        __syncthreads();
    }
    if (t == 0) bsum[blockIdx.x] = r[0];
}

// single-block exclusive scan of bsum[NB] (NB <= 256); writes rowptr[N] = E
__global__ __launch_bounds__(256) void scanB_k(int* __restrict__ bsum,
                                               int* __restrict__ rowptr, int NB, int N) {
    __shared__ int s[2][256];
    int t = threadIdx.x;
    int v = (t < NB) ? bsum[t] : 0;
    int pin = 0;
    s[0][t] = v;
    __syncthreads();
#pragma unroll
    for (int off = 1; off < 256; off <<= 1) {
        int x = s[pin][t];
        if (t >= off) x += s[pin][t - off];
        s[pin ^ 1][t] = x;
        pin ^= 1;
        __syncthreads();
    }
    int incl = s[pin][t];
    if (t < NB) bsum[t] = incl - v;     // exclusive block offset
    if (t == 255) rowptr[N] = incl;     // total = E
}

// in-block exclusive scan of cnt + block offset -> rowptr
__global__ __launch_bounds__(256) void scanC_k(const int* __restrict__ cnt,
                                               const int* __restrict__ bsum,
                                               int* __restrict__ rowptr, int N) {
    __shared__ int s[2][256];
    int t = threadIdx.x, i = blockIdx.x * 256 + t;
    int v = (i < N) ? cnt[i] : 0;
    int pin = 0;
    s[0][t] = v;
    __syncthreads();
#pragma unroll
    for (int off = 1; off < 256; off <<= 1) {
        int x = s[pin][t];
        if (t >= off) x += s[pin][t - off];
        s[pin ^ 1][t] = x;
        pin ^= 1;
        __syncthreads();
    }
    int excl = s[pin][t] - v + bsum[blockIdx.x];
    if (i < N) rowptr[i] = excl;
}

// --- stage 3: stable fill via LDS cursors, ZERO global atomics.
// Block (s,q): cursor[rel] = rowptr[node] + coff[s][node]; places raw
// (src, ew) pairs. dis scaling applied later (degsum_k + scale_k).
__global__ __launch_bounds__(256) void fill_k(const int* __restrict__ row,
                                              const int* __restrict__ col,
                                              const float* __restrict__ ew,
                                              const int* __restrict__ rowptr,
                                              const unsigned short* __restrict__ coff,
                                              int2* __restrict__ pairs, int E, int N) {
    __shared__ int lcur[QN];
    const int t = threadIdx.x;
    const int s = blockIdx.x >> 3;
    const int q = blockIdx.x & 7;
    const int lo = q * QN;
    const unsigned short* cof = coff + (size_t)s * NPAD + lo;
    const int* rp = rowptr + lo;
    for (int i = t; i < QN; i += 256) lcur[i] = rp[i] + (int)cof[i];
    __syncthreads();
    const int per = (E + NSLICE - 1) / NSLICE;
    const int e0 = s * per, e1 = min(E, e0 + per);
    int e = e0 + t;
    for (; e + 768 < e1; e += 1024) {    // 4-deep batched col loads
        int c0 = col[e], c1 = col[e + 256], c2 = col[e + 512], c3 = col[e + 768];
        unsigned r0 = (unsigned)(c0 - lo), r1 = (unsigned)(c1 - lo);
        unsigned r2 = (unsigned)(c2 - lo), r3 = (unsigned)(c3 - lo);
        if (r0 < (unsigned)QN && (unsigned)c0 < (unsigned)N) {
            int r = row[e]; float w = ew[e];
            if ((unsigned)r >= (unsigned)N) { r = 0; w = 0.0f; }
            pairs[atomicAdd(&lcur[r0], 1)] = make_int2(r, __float_as_int(w));
        }
        if (r1 < (unsigned)QN && (unsigned)c1 < (unsigned)N) {
            int r = row[e + 256]; float w = ew[e + 256];
            if ((unsigned)r >= (unsigned)N) { r = 0; w = 0.0f; }
            pairs[atomicAdd(&lcur[r1], 1)] = make_int2(r, __float_as_int(w));
        }
        if (r2 < (unsigned)QN && (unsigned)c2 < (unsigned)N) {
            int r = row[e + 512]; float w = ew[e + 512];
            if ((unsigned)r >= (unsigned)N) { r = 0; w = 0.0f; }
            pairs[atomicAdd(&lcur[r2], 1)] = make_int2(r, __float_as_int(w));
        }
        if (r3 < (unsigned)QN && (unsigned)c3 < (unsigned)N) {
            int r = row[e + 768]; float w = ew[e + 768];
            if ((unsigned)r >= (unsigned)N) { r = 0; w = 0.0f; }
            pairs[atomicAdd(&lcur[r3], 1)] = make_int2(r, __float_as_int(w));
        }
    }
    for (; e < e1; e += 256) {
        int c = col[e];
        unsigned rel = (unsigned)(c - lo);
        if (rel < (unsigned)QN && (unsigned)c < (unsigned)N) {
            int r = row[e]; float w = ew[e];
            if ((unsigned)r >= (unsigned)N) { r = 0; w = 0.0f; }
            pairs[atomicAdd(&lcur[rel], 1)] = make_int2(r, __float_as_int(w));
        }
    }
}

// dis[i] = rsqrt(sum of raw ew over segment + 1)  (coalesced segment sums)
__global__ __launch_bounds__(256) void degsum_k(const int* __restrict__ rowptr,
                                                const int2* __restrict__ pairs,
                                                float* __restrict__ dis, int N) {
    int i = blockIdx.x * 256 + threadIdx.x;
    if (i >= N) return;
    int b = rowptr[i], en = rowptr[i + 1];
    float s = 0.0f;
    for (int e = b; e < en; ++e) s += __int_as_float(pairs[e].y);
    dis[i] = rsqrtf(s + 1.0f);
}

// vals[e] *= dis[src]  (coalesced RW; dis gather is L2-hot, 200KB table)
__global__ __launch_bounds__(256) void scale_k(int2* __restrict__ pairs,
                                               const float* __restrict__ dis, int E) {
    int e = blockIdx.x * 256 + threadIdx.x;
    if (e >= E) return;
    int2 p = pairs[e];
    p.y = __float_as_int(__int_as_float(p.y) * dis[p.x]);
    pairs[e] = p;
}

// out[c,:] = relu( dis[c]*( sum_e val_e*h[src_e,:] + dis[c]*h[c,:] ) + b )
// One wave processes 2 ADJACENT nodes interleaved (contiguous CSR ranges):
// 8 gathers in flight per inner step. lane = feature.
__global__ __launch_bounds__(256) void aggregate_k(const float* __restrict__ h,
                                                   const int* __restrict__ rowptr,
                                                   const int2* __restrict__ pairs,
                                                   const float* __restrict__ dis,
                                                   const float* __restrict__ b,
                                                   float* __restrict__ out, int N) {
    const int t = threadIdx.x;
    const int lane = t & 63;
    const int n0 = (blockIdx.x * 4 + (t >> 6)) * 2;
    if (n0 >= N) return;
    const int n1 = n0 + 1;

    const int beg0 = rowptr[n0];
    const int end0 = rowptr[n0 + 1];
    const int beg1 = end0;
    const int end1 = (n1 < N) ? rowptr[n1 + 1] : end0;
    const int len0 = end0 - beg0, len1 = end1 - beg1;
    const int L = max(len0, len1);

    float acc0 = 0.0f, acc1 = 0.0f;
    for (int base = 0; base < L; base += 64) {
        const int m0 = min(64, len0 - base);   // may be <= 0
        const int m1 = min(64, len1 - base);
        int s0r = 0, s1r = 0; float v0r = 0.0f, v1r = 0.0f;
        if (lane < m0) {
            int2 p = pairs[beg0 + base + lane];
            s0r = p.x; v0r = __int_as_float(p.y);
        }
        if (lane < m1) {
            int2 p = pairs[beg1 + base + lane];
            s1r = p.x; v1r = __int_as_float(p.y);
        }
        const int m = max(m0, m1);
        int j = 0;
        for (; j + 4 <= m; j += 4) {
            int   a0 = __shfl(s0r, j),     a1 = __shfl(s0r, j + 1);
            int   a2 = __shfl(s0r, j + 2), a3 = __shfl(s0r, j + 3);
            int   b0 = __shfl(s1r, j),     b1 = __shfl(s1r, j + 1);
            int   b2 = __shfl(s1r, j + 2), b3 = __shfl(s1r, j + 3);
            float x0 = __shfl(v0r, j),     x1 = __shfl(v0r, j + 1);
            float x2 = __shfl(v0r, j + 2), x3 = __shfl(v0r, j + 3);
            float y0 = __shfl(v1r, j),     y1 = __shfl(v1r, j + 1);
            float y2 = __shfl(v1r, j + 2), y3 = __shfl(v1r, j + 3);
            float ha0 = h[(size_t)a0 * 64 + lane];
            float ha1 = h[(size_t)a1 * 64 + lane];
            float ha2 = h[(size_t)a2 * 64 + lane];
            float ha3 = h[(size_t)a3 * 64 + lane];
            float hb0 = h[(size_t)b0 * 64 + lane];
            float hb1 = h[(size_t)b1 * 64 + lane];
            float hb2 = h[(size_t)b2 * 64 + lane];
            float hb3 = h[(size_t)b3 * 64 + lane];
            acc0 = fmaf(ha0, x0, acc0); acc0 = fmaf(ha1, x1, acc0);
            acc0 = fmaf(ha2, x2, acc0); acc0 = fmaf(ha3, x3, acc0);
            acc1 = fmaf(hb0, y0, acc1); acc1 = fmaf(hb1, y1, acc1);
            acc1 = fmaf(hb2, y2, acc1); acc1 = fmaf(hb3, y3, acc1);
        }
        for (; j < m; ++j) {
            int   a0 = __shfl(s0r, j), b0 = __shfl(s1r, j);
            float x0 = __shfl(v0r, j), y0 = __shfl(v1r, j);
            acc0 = fmaf(h[(size_t)a0 * 64 + lane], x0, acc0);
            acc1 = fmaf(h[(size_t)b0 * 64 + lane], y0, acc1);
        }
    }
    {
        float d = dis[n0];
        acc0 = fmaf(d, h[(size_t)n0 * 64 + lane], acc0);  // inner d (self-loop)
        acc0 = fmaf(d, acc0, b[lane]);                     // outer d + bias
        out[(size_t)n0 * 64 + lane] = fmaxf(acc0, 0.0f);
    }
    if (n1 < N) {
        float d = dis[n1];
        acc1 = fmaf(d, h[(size_t)n1 * 64 + lane], acc1);
        acc1 = fmaf(d, acc1, b[lane]);
        out[(size_t)n1 * 64 + lane] = fmaxf(acc1, 0.0f);
    }
}

// C[M,64] = A[M,K] @ W[K,64], fp32, LDS-tiled. Block = 64 rows, 256 threads,
// each thread a 4x4 micro-tile.
template <int K>
__global__ __launch_bounds__(256) void gemm64_k(const float* __restrict__ A,
                                                const float* __restrict__ W,
                                                float* __restrict__ C, int M) {
    __shared__ float xs[64][68];
    __shared__ float ws[K][64];
    const int t  = threadIdx.x;
    const int n0 = blockIdx.x * 64;

    for (int base = t * 4; base < K * 64; base += 1024)
        *(float4*)((float*)ws + base) = *(const float4*)(W + base);

    const int cg = t & 15, ng = t >> 4;
    const int col = cg * 4, nb = ng * 4;
    float acc[4][4];
#pragma unroll
    for (int i = 0; i < 4; ++i)
#pragma unroll
        for (int j = 0; j < 4; ++j) acc[i][j] = 0.0f;

    for (int k0 = 0; k0 < K; k0 += 64) {
        __syncthreads();
        for (int base = t * 4; base < 64 * 64; base += 1024) {
            int r = base >> 6, k = base & 63;
            int node = n0 + r;
            float4 v = make_float4(0.f, 0.f, 0.f, 0.f);
            if (node < M) v = *(const float4*)(A + (size_t)node * K + k0 + k);
            *(float4*)&xs[r][k] = v;
        }
        __syncthreads();
#pragma unroll 4
        for (int kk = 0; kk < 64; kk += 4) {
            float4 a[4];
#pragma unroll
            for (int i = 0; i < 4; ++i) a[i] = *(float4*)&xs[nb + i][kk];
#pragma unroll
            for (int j = 0; j < 4; ++j) {
                float4 bv = *(float4*)&ws[k0 + kk + j][col];
                float av[4];
                switch (j) {
                    case 0: av[0]=a[0].x; av[1]=a[1].x; av[2]=a[2].x; av[3]=a[3].x; break;
                    case 1: av[0]=a[0].y; av[1]=a[1].y; av[2]=a[2].y; av[3]=a[3].y; break;
                    case 2: av[0]=a[0].z; av[1]=a[1].z; av[2]=a[2].z; av[3]=a[3].z; break;
                    default:av[0]=a[0].w; av[1]=a[1].w; av[2]=a[2].w; av[3]=a[3].w; break;
                }
#pragma unroll
                for (int i = 0; i < 4; ++i) {
                    acc[i][0] = fmaf(av[i], bv.x, acc[i][0]);
                    acc[i][1] = fmaf(av[i], bv.y, acc[i][1]);
                    acc[i][2] = fmaf(av[i], bv.z, acc[i][2]);
                    acc[i][3] = fmaf(av[i], bv.w, acc[i][3]);
                }
            }
        }
    }
#pragma unroll
    for (int i = 0; i < 4; ++i) {
        int node = n0 + nb + i;
        if (node < M)
            *(float4*)(C + (size_t)node * 64 + col) =
                make_float4(acc[i][0], acc[i][1], acc[i][2], acc[i][3]);
    }
}

// Fused 1-step LSTM (h0=c0=0 => skip W_hh and f-gate) + regression head.
// Register-blocked GEMM tile: 64 nodes/block, thread = 4 nodes x 4 cols x
// {i,g,o}. hsT[k][node] transposed so 4 node-activations = one float4 read.
__global__ __launch_bounds__(256) void lstm_head_k(const float* __restrict__ h,
                                                   const float* __restrict__ Wih,
                                                   const float* __restrict__ bih,
                                                   const float* __restrict__ bhh,
                                                   const float* __restrict__ Wreg,
                                                   const float* __restrict__ breg,
                                                   float* __restrict__ out, int N) {
    __shared__ float wt[64 * 192];   // wt[k*192 + gateOff + j] = Wih[gBase+j][k]
    __shared__ float hsT[64 * 64];   // hsT[k*64 + r] = h[n0+r][k]
    const int t = threadIdx.x;
    const int n0 = blockIdx.x * 64;

    {
        const int j = t & 63, kq = (t >> 6) * 4;
#pragma unroll
        for (int gid = 0; gid < 3; ++gid) {
            const int gBase = (gid == 0) ? 0 : (gid == 1 ? 128 : 192);  // i,g,o
            const int gOff = gid * 64;
#pragma unroll
            for (int it = 0; it < 4; ++it) {
                int k0 = it * 16 + kq;
                float4 w = *(const float4*)(Wih + (size_t)(gBase + j) * 64 + k0);
                wt[(k0 + 0) * 192 + gOff + j] = w.x;
                wt[(k0 + 1) * 192 + gOff + j] = w.y;
                wt[(k0 + 2) * 192 + gOff + j] = w.z;
                wt[(k0 + 3) * 192 + gOff + j] = w.w;
            }
        }
    }
    {
        const int r = t & 63, kq = (t >> 6) * 4;
        const int node = n0 + r;
#pragma unroll
        for (int it = 0; it < 4; ++it) {
            int k0 = it * 16 + kq;
            float4 v = make_float4(0.f, 0.f, 0.f, 0.f);
            if (node < N) v = *(const float4*)(h + (size_t)node * 64 + k0);
            hsT[(k0 + 0) * 64 + r] = v.x;
            hsT[(k0 + 1) * 64 + r] = v.y;
            hsT[(k0 + 2) * 64 + r] = v.z;
            hsT[(k0 + 3) * 64 + r] = v.w;
        }
    }

    const int cg = t & 15, ng = t >> 4;
    const int col = cg * 4, nb = ng * 4;
    float4 bi4 = *(const float4*)(bih + col);
    float4 bg4 = *(const float4*)(bih + 128 + col);
    float4 bo4 = *(const float4*)(bih + 192 + col);
    {
        float4 h0 = *(const float4*)(bhh + col);
        float4 h1 = *(const float4*)(bhh + 128 + col);
        float4 h2 = *(const float4*)(bhh + 192 + col);
        bi4.x += h0.x; bi4.y += h0.y; bi4.z += h0.z; bi4.w += h0.w;
        bg4.x += h1.x; bg4.y += h1.y; bg4.z += h1.z; bg4.w += h1.w;
        bo4.x += h2.x; bo4.y += h2.y; bo4.z += h2.z; bo4.w += h2.w;
    }
    float4 wr4 = *(const float4*)(Wreg + col);
    const float br = breg[0];

    __syncthreads();

    float ai[4][4], ag[4][4], ao[4][4];
#pragma unroll
    for (int i = 0; i < 4; ++i)
#pragma unroll
        for (int j = 0; j < 4; ++j) { ai[i][j] = 0.f; ag[i][j] = 0.f; ao[i][j] = 0.f; }

#pragma unroll 4
    for (int k = 0; k < 64; ++k) {
        float4 a  = *(float4*)&hsT[k * 64 + nb];
        float4 wi = *(float4*)&wt[k * 192 + col];
        float4 wg = *(float4*)&wt[k * 192 + 64 + col];
        float4 wo = *(float4*)&wt[k * 192 + 128 + col];
        const float av[4] = {a.x, a.y, a.z, a.w};
#pragma unroll
        for (int i = 0; i < 4; ++i) {
            ai[i][0] = fmaf(av[i], wi.x, ai[i][0]);
            ai[i][1] = fmaf(av[i], wi.y, ai[i][1]);
            ai[i][2] = fmaf(av[i], wi.z, ai[i][2]);
            ai[i][3] = fmaf(av[i], wi.w, ai[i][3]);
            ag[i][0] = fmaf(av[i], wg.x, ag[i][0]);
            ag[i][1] = fmaf(av[i], wg.y, ag[i][1]);
            ag[i][2] = fmaf(av[i], wg.z, ag[i][2]);
            ag[i][3] = fmaf(av[i], wg.w, ag[i][3]);
            ao[i][0] = fmaf(av[i], wo.x, ao[i][0]);
            ao[i][1] = fmaf(av[i], wo.y, ao[i][1]);
            ao[i][2] = fmaf(av[i], wo.z, ao[i][2]);
            ao[i][3] = fmaf(av[i], wo.w, ao[i][3]);
        }
    }

    const float bia[4] = {bi4.x, bi4.y, bi4.z, bi4.w};
    const float bga[4] = {bg4.x, bg4.y, bg4.z, bg4.w};
    const float boa[4] = {bo4.x, bo4.y, bo4.z, bo4.w};
    const float wra[4] = {wr4.x, wr4.y, wr4.z, wr4.w};
    float res[4];
#pragma unroll
    for (int i = 0; i < 4; ++i) {
        float s = 0.f;
#pragma unroll
        for (int j = 0; j < 4; ++j) {
            float gi = ai[i][j] + bia[j];
            float gg = ag[i][j] + bga[j];
            float go = ao[i][j] + boa[j];
            float cc = sigmoidf_(gi) * tanhf(gg);
            float hn = sigmoidf_(go) * tanhf(cc);
            s = fmaf(hn, wra[j], s);
        }
        res[i] = s;
    }
#pragma unroll
    for (int off = 8; off > 0; off >>= 1) {
#pragma unroll
        for (int i = 0; i < 4; ++i) res[i] += __shfl_down(res[i], off);
    }
    if (cg == 0) {
#pragma unroll
        for (int i = 0; i < 4; ++i) {
            int node = n0 + nb + i;
            if (node < N) out[node] = res[i] + br;
        }
    }
}

extern "C" void kernel_launch(void* const* d_in, const int* in_sizes, int n_in,
                              void* d_out, int out_size, void* d_ws, size_t ws_size,
                              hipStream_t stream) {
    const float* x    = (const float*)d_in[0];
    const int*   ei   = (const int*)d_in[1];
    const float* ew   = (const float*)d_in[2];
    const float* W1   = (const float*)d_in[3];
    const float* b1   = (const float*)d_in[4];
    const float* W2   = (const float*)d_in[5];
    const float* b2   = (const float*)d_in[6];
    const float* Wih  = (const float*)d_in[7];
    // d_in[8] = W_hh: unused (h0 = 0)
    const float* bih  = (const float*)d_in[9];
    const float* bhh  = (const float*)d_in[10];
    const float* Wreg = (const float*)d_in[11];
    const float* breg = (const float*)d_in[12];
    float* out = (float*)d_out;

    const int N = out_size;            // O = 1  (N <= NPAD assumed)
    const int E = in_sizes[1] / 2;
    const int* row = ei;
    const int* col = ei + E;

    const int NB = (N + 255) / 256;
    const int eb = (E + 255) / 256;

    // u16 part/coff regions: NSLICE*NPAD*2 B = 12.85 MB each ~= N*64*4 = 12.8 MB
    const size_t R16 = (size_t)NSLICE * NPAD * 2;
    const size_t RF  = (size_t)N * 64 * 4;
    const size_t REG = (R16 > RF ? R16 : RF + 255) & ~(size_t)255;

    char* wsb = (char*)d_ws;
    size_t off = 0;
    // stream-order aliasing: part dead after prefix_k -> bufA (gemm1 out);
    //                        coff dead after fill_k   -> bufC (gemm2 out)
    unsigned short* part = (unsigned short*)(wsb + off);
    float*          bufA = (float*)(wsb + off); off += REG;
    unsigned short* coff = (unsigned short*)(wsb + off);
    float*          bufC = (float*)(wsb + off); off += REG;
    float*          bufB = (float*)(wsb + off); off += REG;
    int2*  pairs  = (int2*) (wsb + off); off += (size_t)E * 8;
    float* dis    = (float*)(wsb + off); off += (size_t)NPAD * 4;
    int*   cnt    = (int*)  (wsb + off); off += (size_t)NPAD * 4;
    int*   rowptr = (int*)  (wsb + off); off += ((size_t)NPAD + 64) * 4;
    int*   bsum   = (int*)  (wsb + off); off += 1024;

    const int gb = (N + 63) / 64;
    const int ab = (N + 7) / 8;        // 2 nodes per wave, 4 waves per block

    // --- CSR-by-destination build (atomic-free, 1024-block parallel) ---
    hist_k<<<NSLICE * NOCT, 256, 0, stream>>>(col, part, E, N);
    prefix_k<<<NPAD / 256, 256, 0, stream>>>(part, coff, cnt);
    scanA_k<<<NB, 256, 0, stream>>>(cnt, bsum, N);
    scanB_k<<<1, 256, 0, stream>>>(bsum, rowptr, NB, N);
    scanC_k<<<NB, 256, 0, stream>>>(cnt, bsum, rowptr, N);
    fill_k<<<NSLICE * NOCT, 256, 0, stream>>>(row, col, ew, rowptr, coff, pairs, E, N);
    degsum_k<<<NB, 256, 0, stream>>>(rowptr, pairs, dis, N);
    scale_k<<<eb, 256, 0, stream>>>(pairs, dis, E);

    // --- GCN layer 1 ---  (bufA aliases part: dead after prefix_k)
    gemm64_k<128><<<gb, 256, 0, stream>>>(x, W1, bufA, N);
    aggregate_k<<<ab, 256, 0, stream>>>(bufA, rowptr, pairs, dis, b1, bufB, N);

    // --- GCN layer 2 ---  (bufC aliases coff: dead after fill_k)
    gemm64_k<64><<<gb, 256, 0, stream>>>(bufB, W2, bufC, N);
    aggregate_k<<<ab, 256, 0, stream>>>(bufC, rowptr, pairs, dis, b2, bufA, N);

    // --- fused LSTM + regression head ---
    lstm_head_k<<<gb, 256, 0, stream>>>(bufA, Wih, bih, bhh, Wreg, breg, out, N);
}